// Round 1
// baseline (864.993 us; speedup 1.0000x reference)
//
#include <hip/hip_runtime.h>
#include <hip/hip_bf16.h>

// ---------- types ----------
typedef __attribute__((ext_vector_type(8))) __bf16 bf16x8;
typedef __attribute__((ext_vector_type(4))) float f32x4;
typedef __attribute__((ext_vector_type(4))) unsigned short us4;

__device__ __forceinline__ unsigned short f2bf(float f) {
    unsigned u = __float_as_uint(f);
    u += 0x7FFFu + ((u >> 16) & 1u);   // RNE
    return (unsigned short)(u >> 16);
}

__device__ __forceinline__ void gload16(const void* g, void* l) {
    __builtin_amdgcn_global_load_lds(
        (const __attribute__((address_space(1))) unsigned int*)g,
        (__attribute__((address_space(3))) unsigned int*)l,
        16, 0, 0);
}

// ---------- kernel 1: fp32 -> bf16 (x) ----------
__global__ void cvt_f32_bf16(const float* __restrict__ in, unsigned short* __restrict__ out, int n4) {
    int i = blockIdx.x * blockDim.x + threadIdx.x;
    if (i >= n4) return;
    float4 v = ((const float4*)in)[i];
    us4 r = { f2bf(v.x), f2bf(v.y), f2bf(v.z), f2bf(v.w) };
    ((us4*)out)[i] = r;
}

// ---------- kernel 2: transpose + convert: in[R][C] f32 -> out[C][R] bf16 ----------
__global__ void tcvt(const float* __restrict__ in, unsigned short* __restrict__ out, int R, int C) {
    __shared__ float tile[32][33];
    int tx = threadIdx.x & 31, ty = threadIdx.x >> 5;  // 256 threads
    int c0 = blockIdx.x * 32, r0 = blockIdx.y * 32;
    #pragma unroll
    for (int i = 0; i < 32; i += 8)
        tile[ty + i][tx] = in[(size_t)(r0 + ty + i) * C + c0 + tx];
    __syncthreads();
    #pragma unroll
    for (int i = 0; i < 32; i += 8)
        out[(size_t)(c0 + ty + i) * R + r0 + tx] = f2bf(tile[tx][ty + i]);
}

// ---------- GEMM (B^T input), 128x128 tile, BK=64, 4 waves ----------
// MODE 0: plain f32 C write.  MODE 1: qkv epilogue (RoPE + scatter to q/k/vT).
template <int MODE>
__global__ __launch_bounds__(256) void gemm_bt(
    const unsigned short* __restrict__ A, const unsigned short* __restrict__ Bt,
    int M, int N, int K, float* __restrict__ Cf,
    unsigned short* __restrict__ qp, unsigned short* __restrict__ kp,
    unsigned short* __restrict__ vTp,
    const float* __restrict__ ropeC, const float* __restrict__ ropeS)
{
    __shared__ unsigned short lA[128 * 64];
    __shared__ unsigned short lB[128 * 64];
    const int tid = threadIdx.x;
    const int lane = tid & 63, wid = tid >> 6;
    const int ln15 = lane & 15, hig = lane >> 4, hi8 = hig * 8;
    const int wr = wid >> 1, wc = wid & 1;
    const int mbase = blockIdx.y * 128, nbase = blockIdx.x * 128;
    const size_t Kb = (size_t)K * 2;

    const char* Ag = (const char*)A + (size_t)(mbase + (tid >> 3)) * Kb + (tid & 7) * 16;
    const char* Bg = (const char*)Bt + (size_t)(nbase + (tid >> 3)) * Kb + (tid & 7) * 16;
    char* lAc = (char*)lA; char* lBc = (char*)lB;

    f32x4 acc[4][4] = {};

    for (int k0 = 0; k0 < K; k0 += 64) {
        #pragma unroll
        for (int i = 0; i < 4; i++) {
            gload16(Ag + (size_t)i * 32 * Kb + (size_t)k0 * 2, lAc + (tid + i * 256) * 16);
            gload16(Bg + (size_t)i * 32 * Kb + (size_t)k0 * 2, lBc + (tid + i * 256) * 16);
        }
        __syncthreads();
        #pragma unroll
        for (int kk = 0; kk < 2; kk++) {
            bf16x8 av[4], bv[4];
            #pragma unroll
            for (int ff = 0; ff < 4; ff++) {
                av[ff] = *(const bf16x8*)(lAc + (((wr * 64 + ff * 16 + ln15) * 64) + kk * 32 + hi8) * 2);
                bv[ff] = *(const bf16x8*)(lBc + (((wc * 64 + ff * 16 + ln15) * 64) + kk * 32 + hi8) * 2);
            }
            #pragma unroll
            for (int mt = 0; mt < 4; mt++)
                #pragma unroll
                for (int nt = 0; nt < 4; nt++)
                    acc[mt][nt] = __builtin_amdgcn_mfma_f32_16x16x32_bf16(av[mt], bv[nt], acc[mt][nt], 0, 0, 0);
        }
        __syncthreads();
    }

    if (MODE == 0) {
        #pragma unroll
        for (int mt = 0; mt < 4; mt++)
            #pragma unroll
            for (int nt = 0; nt < 4; nt++)
                #pragma unroll
                for (int j = 0; j < 4; j++) {
                    int m = mbase + wr * 64 + mt * 16 + hig * 4 + j;
                    int n = nbase + wc * 64 + nt * 16 + ln15;
                    Cf[(size_t)m * N + n] = acc[mt][nt][j];
                }
    } else {
        const int sec = nbase >> 11;              // 0=q, 1=k, 2=v
        const int h = (nbase & 2047) >> 7;        // head (block spans exactly one head)
        if (sec < 2) {
            unsigned short* dst = (sec == 0) ? qp : kp;
            const float scale = (sec == 0) ? 0.08838834764831845f : 1.0f;
            #pragma unroll
            for (int mt = 0; mt < 4; mt++)
                #pragma unroll
                for (int nt = 0; nt < 4; nt++) {
                    int d = wc * 64 + nt * 16 + ln15;
                    int pidx = d >> 1;
                    #pragma unroll
                    for (int j = 0; j < 4; j++) {
                        int m = mbase + wr * 64 + mt * 16 + hig * 4 + j;
                        int b = m >> 11, t = m & 2047;
                        float v = acc[mt][nt][j];
                        float pv = __shfl_xor(v, 1);
                        float c = ropeC[t * 64 + pidx], s = ropeS[t * 64 + pidx];
                        float o = (d & 1) ? fmaf(pv, s, v * c) : fmaf(-pv, s, v * c);
                        o *= scale;
                        dst[((size_t)((b << 4) + h) * 2048 + t) * 128 + d] = f2bf(o);
                    }
                }
        } else {
            #pragma unroll
            for (int mt = 0; mt < 4; mt++)
                #pragma unroll
                for (int nt = 0; nt < 4; nt++) {
                    int d = wc * 64 + nt * 16 + ln15;
                    int m0 = mbase + wr * 64 + mt * 16 + hig * 4;
                    int b = m0 >> 11, t0 = m0 & 2047;
                    us4 pk = { f2bf(acc[mt][nt][0]), f2bf(acc[mt][nt][1]),
                               f2bf(acc[mt][nt][2]), f2bf(acc[mt][nt][3]) };
                    *(us4*)(vTp + ((size_t)((b << 4) + h) * 128 + d) * 2048 + t0) = pk;
                }
        }
    }
}

// ---------- flash attention, causal.  q,k: [BH][T][D] bf16 (q pre-scaled); vT: [BH][D][T] bf16 ----------
__global__ __launch_bounds__(256) void attn_fwd(
    const unsigned short* __restrict__ q, const unsigned short* __restrict__ k,
    const unsigned short* __restrict__ vT, unsigned short* __restrict__ outp)
{
    __shared__ unsigned short lK[64 * 128];   // [kv][d], XOR-swizzled rows (256B)
    __shared__ unsigned short lV[128 * 64];   // [d][kv], XOR-swizzled rows (128B)
    __shared__ unsigned short lP[4 * 32 * 64];
    const int tid = threadIdx.x;
    const int lane = tid & 63, wid = tid >> 6;
    const int ln15 = lane & 15, hig = lane >> 4, hi8 = hig * 8;
    const int bh = blockIdx.y;
    const int qbase = blockIdx.x * 128;
    const int qw = qbase + wid * 32;

    const char* qg = (const char*)(q + (size_t)bh * 2048 * 128);
    const char* kg = (const char*)(k + (size_t)bh * 2048 * 128);
    const char* vg = (const char*)(vT + (size_t)bh * 128 * 2048);
    char* lKc = (char*)lK; char* lVc = (char*)lV;
    char* lPc = (char*)lP + wid * (32 * 64 * 2);

    bf16x8 qf[2][4];
    #pragma unroll
    for (int mt = 0; mt < 2; mt++)
        #pragma unroll
        for (int ks = 0; ks < 4; ks++)
            qf[mt][ks] = *(const bf16x8*)(qg + ((size_t)(qw + mt * 16 + ln15) * 128 + ks * 32 + hi8) * 2);

    f32x4 o[2][8] = {};
    float mreg[2][4], lreg[2][4];
    #pragma unroll
    for (int mt = 0; mt < 2; mt++)
        #pragma unroll
        for (int j = 0; j < 4; j++) { mreg[mt][j] = -1e30f; lreg[mt][j] = 0.f; }

    const int ntiles = (qbase >> 6) + 2;
    for (int it = 0; it < ntiles; it++) {
        const int kv0 = it * 64;
        #pragma unroll
        for (int i = 0; i < 4; i++) {   // K tile: 64 rows x 256B
            int slot = tid + i * 256;
            int row = slot >> 4, c = (slot & 15) * 16;
            gload16(kg + (size_t)(kv0 + row) * 256 + (c ^ ((row & 7) << 4)), lKc + slot * 16);
        }
        #pragma unroll
        for (int i = 0; i < 4; i++) {   // V^T tile: 128 rows x 128B
            int slot = tid + i * 256;
            int d = slot >> 3, c = (slot & 7) * 16;
            gload16(vg + (size_t)d * 4096 + (size_t)kv0 * 2 + (c ^ ((d & 7) << 4)), lVc + slot * 16);
        }
        __syncthreads();

        f32x4 s[2][4] = {};
        #pragma unroll
        for (int ks = 0; ks < 4; ks++) {
            bf16x8 kf[4];
            #pragma unroll
            for (int nt = 0; nt < 4; nt++) {
                int row = nt * 16 + ln15;
                kf[nt] = *(const bf16x8*)(lKc + row * 256 + (((ks * 32 + hi8) * 2) ^ ((row & 7) << 4)));
            }
            #pragma unroll
            for (int mt = 0; mt < 2; mt++)
                #pragma unroll
                for (int nt = 0; nt < 4; nt++)
                    s[mt][nt] = __builtin_amdgcn_mfma_f32_16x16x32_bf16(qf[mt][ks], kf[nt], s[mt][nt], 0, 0, 0);
        }

        if (kv0 + 63 > qw) {  // diagonal / masked tile (wave-uniform)
            #pragma unroll
            for (int mt = 0; mt < 2; mt++)
                #pragma unroll
                for (int nt = 0; nt < 4; nt++)
                    #pragma unroll
                    for (int j = 0; j < 4; j++) {
                        int qi = qw + mt * 16 + hig * 4 + j;
                        int kvi = kv0 + nt * 16 + ln15;
                        if (kvi > qi) s[mt][nt][j] = -1e30f;
                    }
        }

        #pragma unroll
        for (int mt = 0; mt < 2; mt++)
            #pragma unroll
            for (int j = 0; j < 4; j++) {
                float v = fmaxf(fmaxf(s[mt][0][j], s[mt][1][j]), fmaxf(s[mt][2][j], s[mt][3][j]));
                v = fmaxf(v, __shfl_xor(v, 1));
                v = fmaxf(v, __shfl_xor(v, 2));
                v = fmaxf(v, __shfl_xor(v, 4));
                v = fmaxf(v, __shfl_xor(v, 8));
                float mn = fmaxf(mreg[mt][j], v);
                float sc = __expf(mreg[mt][j] - mn);
                mreg[mt][j] = mn;
                lreg[mt][j] *= sc;
                #pragma unroll
                for (int ntd = 0; ntd < 8; ntd++) o[mt][ntd][j] *= sc;
                float rs = 0.f;
                #pragma unroll
                for (int nt = 0; nt < 4; nt++) {
                    float p = __expf(s[mt][nt][j] - mn);
                    s[mt][nt][j] = p;
                    rs += p;
                }
                rs += __shfl_xor(rs, 1);
                rs += __shfl_xor(rs, 2);
                rs += __shfl_xor(rs, 4);
                rs += __shfl_xor(rs, 8);
                lreg[mt][j] += rs;
            }

        // P -> per-wave LDS (bf16, swizzled), then re-fragment for PV
        #pragma unroll
        for (int mt = 0; mt < 2; mt++)
            #pragma unroll
            for (int nt = 0; nt < 4; nt++)
                #pragma unroll
                for (int j = 0; j < 4; j++) {
                    int row = mt * 16 + hig * 4 + j;
                    int addr = row * 128 + (((nt * 16 + ln15) * 2) ^ ((row & 7) << 4));
                    *(unsigned short*)(lPc + addr) = f2bf(s[mt][nt][j]);
                }

        #pragma unroll
        for (int ks2 = 0; ks2 < 2; ks2++) {
            bf16x8 pf[2];
            #pragma unroll
            for (int mt = 0; mt < 2; mt++) {
                int row = mt * 16 + ln15;
                pf[mt] = *(const bf16x8*)(lPc + row * 128 + (((ks2 * 32 + hi8) * 2) ^ ((row & 7) << 4)));
            }
            #pragma unroll
            for (int ntd = 0; ntd < 8; ntd++) {
                int drow = ntd * 16 + ln15;
                bf16x8 vf = *(const bf16x8*)(lVc + drow * 128 + (((ks2 * 32 + hi8) * 2) ^ ((drow & 7) << 4)));
                #pragma unroll
                for (int mt = 0; mt < 2; mt++)
                    o[mt][ntd] = __builtin_amdgcn_mfma_f32_16x16x32_bf16(pf[mt], vf, o[mt][ntd], 0, 0, 0);
            }
        }
        __syncthreads();
    }

    const int b = bh >> 4, h = bh & 15;
    #pragma unroll
    for (int mt = 0; mt < 2; mt++)
        #pragma unroll
        for (int j = 0; j < 4; j++) {
            float inv = 1.0f / lreg[mt][j];
            int t = qw + mt * 16 + hig * 4 + j;
            #pragma unroll
            for (int ntd = 0; ntd < 8; ntd++) {
                int d = ntd * 16 + ln15;
                outp[((size_t)b * 2048 + t) * 2048 + h * 128 + d] = f2bf(o[mt][ntd][j] * inv);
            }
        }
}

// ---------- launcher ----------
extern "C" void kernel_launch(void* const* d_in, const int* in_sizes, int n_in,
                              void* d_out, int out_size, void* d_ws, size_t ws_size,
                              hipStream_t stream) {
    const float* x     = (const float*)d_in[0];
    const float* wqkv  = (const float*)d_in[1];
    const float* wo    = (const float*)d_in[2];
    const float* ropeC = (const float*)d_in[3];
    const float* ropeS = (const float*)d_in[4];
    float* out = (float*)d_out;
    char* ws = (char*)d_ws;
    const size_t MB = 1024 * 1024;
    unsigned short* xb    = (unsigned short*)(ws);                  // 32 MB
    unsigned short* wqkvT = (unsigned short*)(ws + 32 * MB);        // 24 MB
    unsigned short* woT   = (unsigned short*)(ws + 56 * MB);        // 8 MB
    unsigned short* qb    = (unsigned short*)(ws + 64 * MB);        // 32 MB
    unsigned short* kb    = (unsigned short*)(ws + 96 * MB);        // 32 MB
    unsigned short* vTb   = (unsigned short*)(ws + 128 * MB);       // 32 MB
    unsigned short* attnb = (unsigned short*)(ws + 160 * MB);       // 32 MB

    cvt_f32_bf16<<<16384, 256, 0, stream>>>(x, xb, 4194304);
    tcvt<<<dim3(192, 64), 256, 0, stream>>>(wqkv, wqkvT, 2048, 6144);
    tcvt<<<dim3(64, 64), 256, 0, stream>>>(wo, woT, 2048, 2048);
    gemm_bt<1><<<dim3(48, 64), 256, 0, stream>>>(xb, wqkvT, 8192, 6144, 2048,
                                                 nullptr, qb, kb, vTb, ropeC, ropeS);
    attn_fwd<<<dim3(16, 64), 256, 0, stream>>>(qb, kb, vTb, attnb);
    gemm_bt<0><<<dim3(16, 64), 256, 0, stream>>>(attnb, woT, 8192, 2048, 2048,
                                                 out, nullptr, nullptr, nullptr, nullptr, nullptr);
}

// Round 2
// 688.660 us; speedup vs baseline: 1.2561x; 1.2561x over previous
//
#include <hip/hip_runtime.h>
#include <hip/hip_bf16.h>

// ---------- types ----------
typedef __attribute__((ext_vector_type(8))) __bf16 bf16x8;
typedef __attribute__((ext_vector_type(4))) float f32x4;
typedef __attribute__((ext_vector_type(4))) unsigned short us4;

__device__ __forceinline__ unsigned short f2bf(float f) {
    unsigned u = __float_as_uint(f);
    u += 0x7FFFu + ((u >> 16) & 1u);   // RNE
    return (unsigned short)(u >> 16);
}

__device__ __forceinline__ void gload16(const void* g, void* l) {
    __builtin_amdgcn_global_load_lds(
        (const __attribute__((address_space(1))) unsigned int*)g,
        (__attribute__((address_space(3))) unsigned int*)l,
        16, 0, 0);
}

// ---------- kernel 1: fp32 -> bf16 (x) ----------
__global__ void cvt_f32_bf16(const float* __restrict__ in, unsigned short* __restrict__ out, int n4) {
    int i = blockIdx.x * blockDim.x + threadIdx.x;
    if (i >= n4) return;
    float4 v = ((const float4*)in)[i];
    us4 r = { f2bf(v.x), f2bf(v.y), f2bf(v.z), f2bf(v.w) };
    ((us4*)out)[i] = r;
}

// ---------- kernel 2: transpose + convert: in[R][C] f32 -> out[C][R] bf16 ----------
__global__ void tcvt(const float* __restrict__ in, unsigned short* __restrict__ out, int R, int C) {
    __shared__ float tile[32][33];
    int tx = threadIdx.x & 31, ty = threadIdx.x >> 5;  // 256 threads
    int c0 = blockIdx.x * 32, r0 = blockIdx.y * 32;
    #pragma unroll
    for (int i = 0; i < 32; i += 8)
        tile[ty + i][tx] = in[(size_t)(r0 + ty + i) * C + c0 + tx];
    __syncthreads();
    #pragma unroll
    for (int i = 0; i < 32; i += 8)
        out[(size_t)(c0 + ty + i) * R + r0 + tx] = f2bf(tile[tx][ty + i]);
}

// ---------- GEMM (B^T input), 128x128 tile, BK=64, 4 waves, XCD-swizzled ----------
// MODE 0: plain f32 C write.  MODE 1: qkv epilogue (RoPE + scatter to q/k/vT).
template <int MODE>
__global__ __launch_bounds__(256) void gemm_bt(
    const unsigned short* __restrict__ A, const unsigned short* __restrict__ Bt,
    int M, int N, int K, float* __restrict__ Cf,
    unsigned short* __restrict__ qp, unsigned short* __restrict__ kp,
    unsigned short* __restrict__ vTp,
    const float* __restrict__ ropeC, const float* __restrict__ ropeS)
{
    __shared__ unsigned short lA[128 * 64];
    __shared__ unsigned short lB[128 * 64];
    const int tid = threadIdx.x;
    const int lane = tid & 63, wid = tid >> 6;
    const int ln15 = lane & 15, hig = lane >> 4, hi8 = hig * 8;
    const int wr = wid >> 1, wc = wid & 1;

    // XCD-aware swizzle (grids here are always a multiple of 8 blocks)
    int nwg = gridDim.x * gridDim.y;
    int flat = blockIdx.y * gridDim.x + blockIdx.x;
    int swz = ((nwg & 7) == 0) ? ((flat & 7) * (nwg >> 3) + (flat >> 3)) : flat;
    const int bx = swz % gridDim.x, by = swz / gridDim.x;

    const int mbase = by * 128, nbase = bx * 128;
    const size_t Kb = (size_t)K * 2;

    const char* Ag = (const char*)A + (size_t)(mbase + (tid >> 3)) * Kb + (tid & 7) * 16;
    const char* Bg = (const char*)Bt + (size_t)(nbase + (tid >> 3)) * Kb + (tid & 7) * 16;
    char* lAc = (char*)lA; char* lBc = (char*)lB;

    f32x4 acc[4][4] = {};

    for (int k0 = 0; k0 < K; k0 += 64) {
        #pragma unroll
        for (int i = 0; i < 4; i++) {
            gload16(Ag + (size_t)i * 32 * Kb + (size_t)k0 * 2, lAc + (tid + i * 256) * 16);
            gload16(Bg + (size_t)i * 32 * Kb + (size_t)k0 * 2, lBc + (tid + i * 256) * 16);
        }
        __syncthreads();
        #pragma unroll
        for (int kk = 0; kk < 2; kk++) {
            bf16x8 av[4], bv[4];
            #pragma unroll
            for (int ff = 0; ff < 4; ff++) {
                av[ff] = *(const bf16x8*)(lAc + (((wr * 64 + ff * 16 + ln15) * 64) + kk * 32 + hi8) * 2);
                bv[ff] = *(const bf16x8*)(lBc + (((wc * 64 + ff * 16 + ln15) * 64) + kk * 32 + hi8) * 2);
            }
            #pragma unroll
            for (int mt = 0; mt < 4; mt++)
                #pragma unroll
                for (int nt = 0; nt < 4; nt++)
                    acc[mt][nt] = __builtin_amdgcn_mfma_f32_16x16x32_bf16(av[mt], bv[nt], acc[mt][nt], 0, 0, 0);
        }
        __syncthreads();
    }

    if (MODE == 0) {
        #pragma unroll
        for (int mt = 0; mt < 4; mt++)
            #pragma unroll
            for (int nt = 0; nt < 4; nt++)
                #pragma unroll
                for (int j = 0; j < 4; j++) {
                    int m = mbase + wr * 64 + mt * 16 + hig * 4 + j;
                    int n = nbase + wc * 64 + nt * 16 + ln15;
                    Cf[(size_t)m * N + n] = acc[mt][nt][j];
                }
    } else {
        const int sec = nbase >> 11;              // 0=q, 1=k, 2=v
        const int h = (nbase & 2047) >> 7;        // head (block spans exactly one head)
        if (sec < 2) {
            unsigned short* dst = (sec == 0) ? qp : kp;
            const float scale = (sec == 0) ? 0.08838834764831845f : 1.0f;
            #pragma unroll
            for (int mt = 0; mt < 4; mt++)
                #pragma unroll
                for (int nt = 0; nt < 4; nt++) {
                    int d = wc * 64 + nt * 16 + ln15;
                    int pidx = d >> 1;
                    #pragma unroll
                    for (int j = 0; j < 4; j++) {
                        int m = mbase + wr * 64 + mt * 16 + hig * 4 + j;
                        int b = m >> 11, t = m & 2047;
                        float v = acc[mt][nt][j];
                        float pv = __shfl_xor(v, 1);
                        float c = ropeC[t * 64 + pidx], s = ropeS[t * 64 + pidx];
                        float o = (d & 1) ? fmaf(pv, s, v * c) : fmaf(-pv, s, v * c);
                        o *= scale;
                        dst[((size_t)((b << 4) + h) * 2048 + t) * 128 + d] = f2bf(o);
                    }
                }
        } else {
            #pragma unroll
            for (int mt = 0; mt < 4; mt++)
                #pragma unroll
                for (int nt = 0; nt < 4; nt++) {
                    int d = wc * 64 + nt * 16 + ln15;
                    int m0 = mbase + wr * 64 + mt * 16 + hig * 4;
                    int b = m0 >> 11, t0 = m0 & 2047;
                    us4 pk = { f2bf(acc[mt][nt][0]), f2bf(acc[mt][nt][1]),
                               f2bf(acc[mt][nt][2]), f2bf(acc[mt][nt][3]) };
                    *(us4*)(vTp + ((size_t)((b << 4) + h) * 128 + d) * 2048 + t0) = pk;
                }
        }
    }
}

// ---------- flash attention, causal, paired q-tiles for load balance ----------
// q,k: [BH][T][D] bf16 (q pre-scaled); vT: [BH][D][T] bf16
__global__ __launch_bounds__(256) void attn_fwd(
    const unsigned short* __restrict__ q, const unsigned short* __restrict__ k,
    const unsigned short* __restrict__ vT, unsigned short* __restrict__ outp)
{
    __shared__ unsigned short lK[64 * 128];   // [kv][d], XOR-swizzled rows (256B)
    __shared__ unsigned short lV[128 * 64];   // [d][kv], XOR-swizzled rows (128B)
    __shared__ unsigned short lP[4 * 32 * 64];
    const int tid = threadIdx.x;
    const int lane = tid & 63, wid = tid >> 6;
    const int ln15 = lane & 15, hig = lane >> 4, hi8 = hig * 8;
    const int bh = blockIdx.y;

    const char* qg = (const char*)(q + (size_t)bh * 2048 * 128);
    const char* kg = (const char*)(k + (size_t)bh * 2048 * 128);
    const char* vg = (const char*)(vT + (size_t)bh * 128 * 2048);
    char* lKc = (char*)lK; char* lVc = (char*)lV;
    char* lPc = (char*)lP + wid * (32 * 64 * 2);
    const int b = bh >> 4, h = bh & 15;

    // Two q-tiles per block: x and 15-x  ->  every block does 34 tile-iters.
    for (int rep = 0; rep < 2; rep++) {
        const int qt = rep == 0 ? (int)blockIdx.x : 15 - (int)blockIdx.x;
        const int qbase = qt * 128;
        const int qw = qbase + wid * 32;

        bf16x8 qf[2][4];
        #pragma unroll
        for (int mt = 0; mt < 2; mt++)
            #pragma unroll
            for (int ks = 0; ks < 4; ks++)
                qf[mt][ks] = *(const bf16x8*)(qg + ((size_t)(qw + mt * 16 + ln15) * 128 + ks * 32 + hi8) * 2);

        f32x4 o[2][8] = {};
        float mreg[2][4], lreg[2][4];
        #pragma unroll
        for (int mt = 0; mt < 2; mt++)
            #pragma unroll
            for (int j = 0; j < 4; j++) { mreg[mt][j] = -1e30f; lreg[mt][j] = 0.f; }

        const int ntiles = (qbase >> 6) + 2;
        for (int it = 0; it < ntiles; it++) {
            const int kv0 = it * 64;
            #pragma unroll
            for (int i = 0; i < 4; i++) {   // K tile: 64 rows x 256B
                int slot = tid + i * 256;
                int row = slot >> 4, c = (slot & 15) * 16;
                gload16(kg + (size_t)(kv0 + row) * 256 + (c ^ ((row & 7) << 4)), lKc + slot * 16);
            }
            #pragma unroll
            for (int i = 0; i < 4; i++) {   // V^T tile: 128 rows x 128B
                int slot = tid + i * 256;
                int d = slot >> 3, c = (slot & 7) * 16;
                gload16(vg + (size_t)d * 4096 + (size_t)kv0 * 2 + (c ^ ((d & 7) << 4)), lVc + slot * 16);
            }
            __syncthreads();

            f32x4 s[2][4] = {};
            #pragma unroll
            for (int ks = 0; ks < 4; ks++) {
                bf16x8 kf[4];
                #pragma unroll
                for (int nt = 0; nt < 4; nt++) {
                    int row = nt * 16 + ln15;
                    kf[nt] = *(const bf16x8*)(lKc + row * 256 + (((ks * 32 + hi8) * 2) ^ ((row & 7) << 4)));
                }
                #pragma unroll
                for (int mt = 0; mt < 2; mt++)
                    #pragma unroll
                    for (int nt = 0; nt < 4; nt++)
                        s[mt][nt] = __builtin_amdgcn_mfma_f32_16x16x32_bf16(qf[mt][ks], kf[nt], s[mt][nt], 0, 0, 0);
            }

            if (kv0 + 63 > qw) {  // diagonal / masked tile (wave-uniform)
                #pragma unroll
                for (int mt = 0; mt < 2; mt++)
                    #pragma unroll
                    for (int nt = 0; nt < 4; nt++)
                        #pragma unroll
                        for (int j = 0; j < 4; j++) {
                            int qi = qw + mt * 16 + hig * 4 + j;
                            int kvi = kv0 + nt * 16 + ln15;
                            if (kvi > qi) s[mt][nt][j] = -1e30f;
                        }
            }

            #pragma unroll
            for (int mt = 0; mt < 2; mt++)
                #pragma unroll
                for (int j = 0; j < 4; j++) {
                    float v = fmaxf(fmaxf(s[mt][0][j], s[mt][1][j]), fmaxf(s[mt][2][j], s[mt][3][j]));
                    v = fmaxf(v, __shfl_xor(v, 1));
                    v = fmaxf(v, __shfl_xor(v, 2));
                    v = fmaxf(v, __shfl_xor(v, 4));
                    v = fmaxf(v, __shfl_xor(v, 8));
                    float mn = fmaxf(mreg[mt][j], v);
                    float sc = __expf(mreg[mt][j] - mn);
                    mreg[mt][j] = mn;
                    lreg[mt][j] *= sc;
                    #pragma unroll
                    for (int ntd = 0; ntd < 8; ntd++) o[mt][ntd][j] *= sc;
                    float rs = 0.f;
                    #pragma unroll
                    for (int nt = 0; nt < 4; nt++) {
                        float p = __expf(s[mt][nt][j] - mn);
                        s[mt][nt][j] = p;
                        rs += p;
                    }
                    rs += __shfl_xor(rs, 1);
                    rs += __shfl_xor(rs, 2);
                    rs += __shfl_xor(rs, 4);
                    rs += __shfl_xor(rs, 8);
                    lreg[mt][j] += rs;
                }

            // P -> per-wave LDS (bf16, swizzled), then re-fragment for PV
            #pragma unroll
            for (int mt = 0; mt < 2; mt++)
                #pragma unroll
                for (int nt = 0; nt < 4; nt++)
                    #pragma unroll
                    for (int j = 0; j < 4; j++) {
                        int row = mt * 16 + hig * 4 + j;
                        int addr = row * 128 + (((nt * 16 + ln15) * 2) ^ ((row & 7) << 4));
                        *(unsigned short*)(lPc + addr) = f2bf(s[mt][nt][j]);
                    }

            #pragma unroll
            for (int ks2 = 0; ks2 < 2; ks2++) {
                bf16x8 pf[2];
                #pragma unroll
                for (int mt = 0; mt < 2; mt++) {
                    int row = mt * 16 + ln15;
                    pf[mt] = *(const bf16x8*)(lPc + row * 128 + (((ks2 * 32 + hi8) * 2) ^ ((row & 7) << 4)));
                }
                #pragma unroll
                for (int ntd = 0; ntd < 8; ntd++) {
                    int drow = ntd * 16 + ln15;
                    bf16x8 vf = *(const bf16x8*)(lVc + drow * 128 + (((ks2 * 32 + hi8) * 2) ^ ((drow & 7) << 4)));
                    #pragma unroll
                    for (int mt = 0; mt < 2; mt++)
                        o[mt][ntd] = __builtin_amdgcn_mfma_f32_16x16x32_bf16(pf[mt], vf, o[mt][ntd], 0, 0, 0);
                }
            }
            __syncthreads();
        }

        #pragma unroll
        for (int mt = 0; mt < 2; mt++)
            #pragma unroll
            for (int j = 0; j < 4; j++) {
                float inv = 1.0f / lreg[mt][j];
                int t = qw + mt * 16 + hig * 4 + j;
                #pragma unroll
                for (int ntd = 0; ntd < 8; ntd++) {
                    int d = ntd * 16 + ln15;
                    outp[((size_t)b * 2048 + t) * 2048 + h * 128 + d] = f2bf(o[mt][ntd][j] * inv);
                }
            }
    }
}

// ---------- launcher ----------
extern "C" void kernel_launch(void* const* d_in, const int* in_sizes, int n_in,
                              void* d_out, int out_size, void* d_ws, size_t ws_size,
                              hipStream_t stream) {
    const float* x     = (const float*)d_in[0];
    const float* wqkv  = (const float*)d_in[1];
    const float* wo    = (const float*)d_in[2];
    const float* ropeC = (const float*)d_in[3];
    const float* ropeS = (const float*)d_in[4];
    float* out = (float*)d_out;
    char* ws = (char*)d_ws;
    const size_t MB = 1024 * 1024;
    unsigned short* xb    = (unsigned short*)(ws);                  // 32 MB
    unsigned short* wqkvT = (unsigned short*)(ws + 32 * MB);        // 24 MB
    unsigned short* woT   = (unsigned short*)(ws + 56 * MB);        // 8 MB
    unsigned short* qb    = (unsigned short*)(ws + 64 * MB);        // 32 MB
    unsigned short* kb    = (unsigned short*)(ws + 96 * MB);        // 32 MB
    unsigned short* vTb   = (unsigned short*)(ws + 128 * MB);       // 32 MB
    unsigned short* attnb = (unsigned short*)(ws + 160 * MB);       // 32 MB

    cvt_f32_bf16<<<16384, 256, 0, stream>>>(x, xb, 4194304);
    tcvt<<<dim3(192, 64), 256, 0, stream>>>(wqkv, wqkvT, 2048, 6144);
    tcvt<<<dim3(64, 64), 256, 0, stream>>>(wo, woT, 2048, 2048);
    gemm_bt<1><<<dim3(48, 64), 256, 0, stream>>>(xb, wqkvT, 8192, 6144, 2048,
                                                 nullptr, qb, kb, vTb, ropeC, ropeS);
    attn_fwd<<<dim3(8, 64), 256, 0, stream>>>(qb, kb, vTb, attnb);
    gemm_bt<0><<<dim3(16, 64), 256, 0, stream>>>(attnb, woT, 8192, 2048, 2048,
                                                 out, nullptr, nullptr, nullptr, nullptr, nullptr);
}

// Round 3
// 563.458 us; speedup vs baseline: 1.5351x; 1.2222x over previous
//
#include <hip/hip_runtime.h>
#include <hip/hip_bf16.h>

// ---------- types ----------
typedef __attribute__((ext_vector_type(8))) __bf16 bf16x8;
typedef __attribute__((ext_vector_type(4))) float f32x4;
typedef __attribute__((ext_vector_type(4))) unsigned short us4;

__device__ __forceinline__ unsigned short f2bf(float f) {
    unsigned u = __float_as_uint(f);
    u += 0x7FFFu + ((u >> 16) & 1u);   // RNE
    return (unsigned short)(u >> 16);
}

__device__ __forceinline__ void gload16(const void* g, void* l) {
    __builtin_amdgcn_global_load_lds(
        (const __attribute__((address_space(1))) unsigned int*)g,
        (__attribute__((address_space(3))) unsigned int*)l,
        16, 0, 0);
}

// ---------- kernel 1: fp32 -> bf16 (x) ----------
__global__ void cvt_f32_bf16(const float* __restrict__ in, unsigned short* __restrict__ out, int n4) {
    int i = blockIdx.x * blockDim.x + threadIdx.x;
    if (i >= n4) return;
    float4 v = ((const float4*)in)[i];
    us4 r = { f2bf(v.x), f2bf(v.y), f2bf(v.z), f2bf(v.w) };
    ((us4*)out)[i] = r;
}

// ---------- kernel 2: transpose + convert: in[R][C] f32 -> out[C][R] bf16 ----------
__global__ void tcvt(const float* __restrict__ in, unsigned short* __restrict__ out, int R, int C) {
    __shared__ float tile[32][33];
    int tx = threadIdx.x & 31, ty = threadIdx.x >> 5;  // 256 threads
    int c0 = blockIdx.x * 32, r0 = blockIdx.y * 32;
    #pragma unroll
    for (int i = 0; i < 32; i += 8)
        tile[ty + i][tx] = in[(size_t)(r0 + ty + i) * C + c0 + tx];
    __syncthreads();
    #pragma unroll
    for (int i = 0; i < 32; i += 8)
        out[(size_t)(c0 + ty + i) * R + r0 + tx] = f2bf(tile[tx][ty + i]);
}

// ---------- 256x256 8-phase GEMM (B^T input), BK=64 (2x 32-k panels), 512 thr ----------
// LDS: lA/lB = [2 buf][2 kk-panel][256 rows][32 bf16], rows 64B, swizzle:
//   16B-slot g of row r holds k-group g ^ ((r>>3&1)<<1)  (st_16x32: byte^=((byte>>9)&1)<<5)
// MODE 0: f32 C write.  MODE 1: qkv epilogue (RoPE + scatter to q/k/vT).
#define MF(af, bf, fi, ni) acc[fi][ni] = __builtin_amdgcn_mfma_f32_16x16x32_bf16(af, bf, acc[fi][ni], 0, 0, 0)
#define LOADA(p, off) do { a0 = *(const bf16x8*)((p)+(off)); a1 = *(const bf16x8*)((p)+(off)+1024); \
                           a2 = *(const bf16x8*)((p)+(off)+2048); a3 = *(const bf16x8*)((p)+(off)+3072); } while(0)
#define LOADB(p) do { b0 = *(const bf16x8*)(p); b1 = *(const bf16x8*)((p)+1024); \
                      b2 = *(const bf16x8*)((p)+2048); b3 = *(const bf16x8*)((p)+3072); } while(0)
#define MFMA16(base) do { \
    MF(a0,b0,(base)+0,0); MF(a0,b1,(base)+0,1); MF(a0,b2,(base)+0,2); MF(a0,b3,(base)+0,3); \
    MF(a1,b0,(base)+1,0); MF(a1,b1,(base)+1,1); MF(a1,b2,(base)+1,2); MF(a1,b3,(base)+1,3); \
    MF(a2,b0,(base)+2,0); MF(a2,b1,(base)+2,1); MF(a2,b2,(base)+2,2); MF(a2,b3,(base)+2,3); \
    MF(a3,b0,(base)+3,0); MF(a3,b1,(base)+3,1); MF(a3,b2,(base)+3,2); MF(a3,b3,(base)+3,3); } while(0)
#define STG(gb, lp, buf, kkk, kt) do { \
    size_t ko = (size_t)(kt) * 128 + (kkk) * 64; \
    char* lpp = (lp) + (buf) * 32768 + (kkk) * 16384; \
    gload16((gb) + sR0 + ko, lpp + dst0); \
    gload16((gb) + sR1 + ko, lpp + dst1); } while (0)

template <int MODE>
__global__ __launch_bounds__(512) void gemm8p(
    const unsigned short* __restrict__ A, const unsigned short* __restrict__ Bt,
    int M, int N, int K, float* __restrict__ Cf,
    unsigned short* __restrict__ qp, unsigned short* __restrict__ kp,
    unsigned short* __restrict__ vTp,
    const float* __restrict__ ropeC, const float* __restrict__ ropeS)
{
    __shared__ unsigned short lA[2][2][8192];   // 64 KB
    __shared__ unsigned short lB[2][2][8192];   // 64 KB
    const int tid = threadIdx.x;
    const int lane = tid & 63, wid = tid >> 6;
    const int ln15 = lane & 15, hig = lane >> 4;
    const int wr = wid >> 2, wc = wid & 3;

    int nwg = gridDim.x * gridDim.y;
    int flat = blockIdx.y * gridDim.x + blockIdx.x;
    int swz = ((nwg & 7) == 0) ? ((flat & 7) * (nwg >> 3) + (flat >> 3)) : flat;
    const int bx = swz % gridDim.x, by = swz / gridDim.x;
    const int mbase = by * 256, nbase = bx * 256;
    const size_t Kb = (size_t)K * 2;

    const char* Ag = (const char*)A + (size_t)mbase * Kb;
    const char* Bg = (const char*)Bt + (size_t)nbase * Kb;
    char* lAc = (char*)&lA[0][0][0];
    char* lBc = (char*)&lB[0][0][0];

    // staging constants: thread covers (row = tid>>2, g = tid&3) and row+128
    const int srow = tid >> 2;
    const int gsrc = (tid & 3) ^ (((tid >> 5) & 1) << 1);   // inverse-swizzled k-group
    const size_t sR0 = (size_t)srow * Kb + gsrc * 16;
    const size_t sR1 = (size_t)(srow + 128) * Kb + gsrc * 16;
    const int dst0 = tid * 16, dst1 = (tid + 512) * 16;

    // read-side per-lane offsets (swizzled)
    const int colOff = (hig * 16) ^ (((ln15 >> 3) & 1) << 5);
    const int aRow = (wr * 128 + ln15) * 64 + colOff;
    const int bRow = (wc * 64 + ln15) * 64 + colOff;

    f32x4 acc[8][4] = {};
    const int T = K >> 6;

    // prologue: A0k0, B0k0, A0k1, B0k1, A1k0, B1k0  (6 halves, 12 loads)
    STG(Ag, lAc, 0, 0, 0);
    STG(Bg, lBc, 0, 0, 0);
    STG(Ag, lAc, 0, 1, 0);
    STG(Bg, lBc, 0, 1, 0);
    STG(Ag, lAc, 1, 0, 1);
    STG(Bg, lBc, 1, 0, 1);
    asm volatile("s_waitcnt vmcnt(8)" ::: "memory");
    __builtin_amdgcn_s_barrier();

    for (int t = 0; t < T; t++) {
        const int cur = t & 1, nxt = cur ^ 1;
        const char* pa0 = lAc + cur * 32768 + aRow;
        const char* pb0 = lBc + cur * 32768 + bRow;
        const char* pa1 = pa0 + 16384;
        const char* pb1 = pb0 + 16384;
        const bool tail = (t >= T - 2);
        bf16x8 a0, a1, a2, a3, b0, b1, b2, b3;

        // ---- ph1: (m-half0, kk0) ----
        LOADA(pa0, 0);
        LOADB(pb0);
        if (t + 1 < T) STG(Ag, lAc, nxt, 1, t + 1);
        __builtin_amdgcn_s_barrier();
        __builtin_amdgcn_s_setprio(1);
        MFMA16(0);
        __builtin_amdgcn_s_setprio(0);
        __builtin_amdgcn_s_barrier();

        // ---- ph2: (m-half1, kk0) ----
        LOADA(pa0, 4096);
        if (t + 1 < T) STG(Bg, lBc, nxt, 1, t + 1);
        if (tail) asm volatile("s_waitcnt vmcnt(0)" ::: "memory");
        else      asm volatile("s_waitcnt vmcnt(6)" ::: "memory");
        __builtin_amdgcn_s_barrier();
        __builtin_amdgcn_s_setprio(1);
        MFMA16(4);
        __builtin_amdgcn_s_setprio(0);
        __builtin_amdgcn_s_barrier();

        // ---- ph3: (m-half0, kk1) ----
        LOADA(pa1, 0);
        LOADB(pb1);
        if (t + 2 < T) STG(Ag, lAc, cur, 0, t + 2);
        __builtin_amdgcn_s_barrier();
        __builtin_amdgcn_s_setprio(1);
        MFMA16(0);
        __builtin_amdgcn_s_setprio(0);
        __builtin_amdgcn_s_barrier();

        // ---- ph4: (m-half1, kk1) ----
        LOADA(pa1, 4096);
        if (t + 2 < T) STG(Bg, lBc, cur, 0, t + 2);
        if (tail) asm volatile("s_waitcnt vmcnt(0)" ::: "memory");
        else      asm volatile("s_waitcnt vmcnt(6)" ::: "memory");
        __builtin_amdgcn_s_barrier();
        __builtin_amdgcn_s_setprio(1);
        MFMA16(4);
        __builtin_amdgcn_s_setprio(0);
        __builtin_amdgcn_s_barrier();
    }

    if (MODE == 0) {
        #pragma unroll
        for (int fg = 0; fg < 8; fg++)
            #pragma unroll
            for (int n = 0; n < 4; n++)
                #pragma unroll
                for (int j = 0; j < 4; j++) {
                    int m = mbase + wr * 128 + fg * 16 + hig * 4 + j;
                    int col = nbase + wc * 64 + n * 16 + ln15;
                    Cf[(size_t)m * N + col] = acc[fg][n][j];
                }
    } else {
        const int colb = nbase + wc * 64;
        const int sec = colb >> 11;               // 0=q, 1=k, 2=v (block range within one sec)
        if (sec < 2) {
            unsigned short* dst = (sec == 0) ? qp : kp;
            const float scale = (sec == 0) ? 0.08838834764831845f : 1.0f;
            #pragma unroll
            for (int fg = 0; fg < 8; fg++)
                #pragma unroll
                for (int n = 0; n < 4; n++) {
                    int within = (colb & 2047) + n * 16 + ln15;
                    int h = within >> 7, d = within & 127, pidx = d >> 1;
                    #pragma unroll
                    for (int j = 0; j < 4; j++) {
                        int m = mbase + wr * 128 + fg * 16 + hig * 4 + j;
                        int b = m >> 11, tq = m & 2047;
                        float v = acc[fg][n][j];
                        float pv = __shfl_xor(v, 1);
                        float c = ropeC[tq * 64 + pidx], s = ropeS[tq * 64 + pidx];
                        float o = (d & 1) ? fmaf(pv, s, v * c) : fmaf(-pv, s, v * c);
                        o *= scale;
                        dst[((size_t)((b << 4) + h) * 2048 + tq) * 128 + d] = f2bf(o);
                    }
                }
        } else {
            #pragma unroll
            for (int fg = 0; fg < 8; fg++)
                #pragma unroll
                for (int n = 0; n < 4; n++) {
                    int within = (colb & 2047) + n * 16 + ln15;
                    int h = within >> 7, d = within & 127;
                    int m0 = mbase + wr * 128 + fg * 16 + hig * 4;
                    int b = m0 >> 11, t0 = m0 & 2047;
                    us4 pk = { f2bf(acc[fg][n][0]), f2bf(acc[fg][n][1]),
                               f2bf(acc[fg][n][2]), f2bf(acc[fg][n][3]) };
                    *(us4*)(vTp + ((size_t)((b << 4) + h) * 128 + d) * 2048 + t0) = pk;
                }
        }
    }
}

// ---------- flash attention, causal, paired q-tiles for load balance ----------
// q,k: [BH][T][D] bf16 (q pre-scaled); vT: [BH][D][T] bf16
__global__ __launch_bounds__(256) void attn_fwd(
    const unsigned short* __restrict__ q, const unsigned short* __restrict__ k,
    const unsigned short* __restrict__ vT, unsigned short* __restrict__ outp)
{
    __shared__ unsigned short lK[64 * 128];   // [kv][d], XOR-swizzled rows (256B)
    __shared__ unsigned short lV[128 * 64];   // [d][kv], XOR-swizzled rows (128B)
    __shared__ unsigned short lP[4 * 32 * 64];
    const int tid = threadIdx.x;
    const int lane = tid & 63, wid = tid >> 6;
    const int ln15 = lane & 15, hig = lane >> 4, hi8 = hig * 8;
    const int bh = blockIdx.y;

    const char* qg = (const char*)(q + (size_t)bh * 2048 * 128);
    const char* kg = (const char*)(k + (size_t)bh * 2048 * 128);
    const char* vg = (const char*)(vT + (size_t)bh * 128 * 2048);
    char* lKc = (char*)lK; char* lVc = (char*)lV;
    char* lPc = (char*)lP + wid * (32 * 64 * 2);
    const int b = bh >> 4, h = bh & 15;

    for (int rep = 0; rep < 2; rep++) {
        const int qt = rep == 0 ? (int)blockIdx.x : 15 - (int)blockIdx.x;
        const int qbase = qt * 128;
        const int qw = qbase + wid * 32;

        bf16x8 qf[2][4];
        #pragma unroll
        for (int mt = 0; mt < 2; mt++)
            #pragma unroll
            for (int ks = 0; ks < 4; ks++)
                qf[mt][ks] = *(const bf16x8*)(qg + ((size_t)(qw + mt * 16 + ln15) * 128 + ks * 32 + hi8) * 2);

        f32x4 o[2][8] = {};
        float mreg[2][4], lreg[2][4];
        #pragma unroll
        for (int mt = 0; mt < 2; mt++)
            #pragma unroll
            for (int j = 0; j < 4; j++) { mreg[mt][j] = -1e30f; lreg[mt][j] = 0.f; }

        const int ntiles = (qbase >> 6) + 2;
        for (int it = 0; it < ntiles; it++) {
            const int kv0 = it * 64;
            #pragma unroll
            for (int i = 0; i < 4; i++) {   // K tile: 64 rows x 256B
                int slot = tid + i * 256;
                int row = slot >> 4, c = (slot & 15) * 16;
                gload16(kg + (size_t)(kv0 + row) * 256 + (c ^ ((row & 7) << 4)), lKc + slot * 16);
            }
            #pragma unroll
            for (int i = 0; i < 4; i++) {   // V^T tile: 128 rows x 128B
                int slot = tid + i * 256;
                int d = slot >> 3, c = (slot & 7) * 16;
                gload16(vg + (size_t)d * 4096 + (size_t)kv0 * 2 + (c ^ ((d & 7) << 4)), lVc + slot * 16);
            }
            __syncthreads();

            f32x4 s[2][4] = {};
            #pragma unroll
            for (int ks = 0; ks < 4; ks++) {
                bf16x8 kf[4];
                #pragma unroll
                for (int nt = 0; nt < 4; nt++) {
                    int row = nt * 16 + ln15;
                    kf[nt] = *(const bf16x8*)(lKc + row * 256 + (((ks * 32 + hi8) * 2) ^ ((row & 7) << 4)));
                }
                #pragma unroll
                for (int mt = 0; mt < 2; mt++)
                    #pragma unroll
                    for (int nt = 0; nt < 4; nt++)
                        s[mt][nt] = __builtin_amdgcn_mfma_f32_16x16x32_bf16(qf[mt][ks], kf[nt], s[mt][nt], 0, 0, 0);
            }

            if (kv0 + 63 > qw) {  // diagonal / masked tile (wave-uniform)
                #pragma unroll
                for (int mt = 0; mt < 2; mt++)
                    #pragma unroll
                    for (int nt = 0; nt < 4; nt++)
                        #pragma unroll
                        for (int j = 0; j < 4; j++) {
                            int qi = qw + mt * 16 + hig * 4 + j;
                            int kvi = kv0 + nt * 16 + ln15;
                            if (kvi > qi) s[mt][nt][j] = -1e30f;
                        }
            }

            #pragma unroll
            for (int mt = 0; mt < 2; mt++)
                #pragma unroll
                for (int j = 0; j < 4; j++) {
                    float v = fmaxf(fmaxf(s[mt][0][j], s[mt][1][j]), fmaxf(s[mt][2][j], s[mt][3][j]));
                    v = fmaxf(v, __shfl_xor(v, 1));
                    v = fmaxf(v, __shfl_xor(v, 2));
                    v = fmaxf(v, __shfl_xor(v, 4));
                    v = fmaxf(v, __shfl_xor(v, 8));
                    float mn = fmaxf(mreg[mt][j], v);
                    float sc = __expf(mreg[mt][j] - mn);
                    mreg[mt][j] = mn;
                    lreg[mt][j] *= sc;
                    #pragma unroll
                    for (int ntd = 0; ntd < 8; ntd++) o[mt][ntd][j] *= sc;
                    float rs = 0.f;
                    #pragma unroll
                    for (int nt = 0; nt < 4; nt++) {
                        float p = __expf(s[mt][nt][j] - mn);
                        s[mt][nt][j] = p;
                        rs += p;
                    }
                    rs += __shfl_xor(rs, 1);
                    rs += __shfl_xor(rs, 2);
                    rs += __shfl_xor(rs, 4);
                    rs += __shfl_xor(rs, 8);
                    lreg[mt][j] += rs;
                }

            #pragma unroll
            for (int mt = 0; mt < 2; mt++)
                #pragma unroll
                for (int nt = 0; nt < 4; nt++)
                    #pragma unroll
                    for (int j = 0; j < 4; j++) {
                        int row = mt * 16 + hig * 4 + j;
                        int addr = row * 128 + (((nt * 16 + ln15) * 2) ^ ((row & 7) << 4));
                        *(unsigned short*)(lPc + addr) = f2bf(s[mt][nt][j]);
                    }

            #pragma unroll
            for (int ks2 = 0; ks2 < 2; ks2++) {
                bf16x8 pf[2];
                #pragma unroll
                for (int mt = 0; mt < 2; mt++) {
                    int row = mt * 16 + ln15;
                    pf[mt] = *(const bf16x8*)(lPc + row * 128 + (((ks2 * 32 + hi8) * 2) ^ ((row & 7) << 4)));
                }
                #pragma unroll
                for (int ntd = 0; ntd < 8; ntd++) {
                    int drow = ntd * 16 + ln15;
                    bf16x8 vf = *(const bf16x8*)(lVc + drow * 128 + (((ks2 * 32 + hi8) * 2) ^ ((drow & 7) << 4)));
                    #pragma unroll
                    for (int mt = 0; mt < 2; mt++)
                        o[mt][ntd] = __builtin_amdgcn_mfma_f32_16x16x32_bf16(pf[mt], vf, o[mt][ntd], 0, 0, 0);
                }
            }
            __syncthreads();
        }

        #pragma unroll
        for (int mt = 0; mt < 2; mt++)
            #pragma unroll
            for (int j = 0; j < 4; j++) {
                float inv = 1.0f / lreg[mt][j];
                int t = qw + mt * 16 + hig * 4 + j;
                #pragma unroll
                for (int ntd = 0; ntd < 8; ntd++) {
                    int d = ntd * 16 + ln15;
                    outp[((size_t)b * 2048 + t) * 2048 + h * 128 + d] = f2bf(o[mt][ntd][j] * inv);
                }
            }
    }
}

// ---------- launcher ----------
extern "C" void kernel_launch(void* const* d_in, const int* in_sizes, int n_in,
                              void* d_out, int out_size, void* d_ws, size_t ws_size,
                              hipStream_t stream) {
    const float* x     = (const float*)d_in[0];
    const float* wqkv  = (const float*)d_in[1];
    const float* wo    = (const float*)d_in[2];
    const float* ropeC = (const float*)d_in[3];
    const float* ropeS = (const float*)d_in[4];
    float* out = (float*)d_out;
    char* ws = (char*)d_ws;
    const size_t MB = 1024 * 1024;
    unsigned short* xb    = (unsigned short*)(ws);                  // 32 MB
    unsigned short* wqkvT = (unsigned short*)(ws + 32 * MB);        // 24 MB
    unsigned short* woT   = (unsigned short*)(ws + 56 * MB);        // 8 MB
    unsigned short* qb    = (unsigned short*)(ws + 64 * MB);        // 32 MB
    unsigned short* kb    = (unsigned short*)(ws + 96 * MB);        // 32 MB
    unsigned short* vTb   = (unsigned short*)(ws + 128 * MB);       // 32 MB
    unsigned short* attnb = (unsigned short*)(ws + 160 * MB);       // 32 MB

    cvt_f32_bf16<<<16384, 256, 0, stream>>>(x, xb, 4194304);
    tcvt<<<dim3(192, 64), 256, 0, stream>>>(wqkv, wqkvT, 2048, 6144);
    tcvt<<<dim3(64, 64), 256, 0, stream>>>(wo, woT, 2048, 2048);
    gemm8p<1><<<dim3(24, 32), 512, 0, stream>>>(xb, wqkvT, 8192, 6144, 2048,
                                                nullptr, qb, kb, vTb, ropeC, ropeS);
    attn_fwd<<<dim3(8, 64), 256, 0, stream>>>(qb, kb, vTb, attnb);
    gemm8p<0><<<dim3(8, 32), 512, 0, stream>>>(attnb, woT, 8192, 2048, 2048,
                                               out, nullptr, nullptr, nullptr, nullptr, nullptr);
}

// Round 4
// 561.779 us; speedup vs baseline: 1.5397x; 1.0030x over previous
//
#include <hip/hip_runtime.h>
#include <hip/hip_bf16.h>

// ---------- types ----------
typedef __attribute__((ext_vector_type(8))) __bf16 bf16x8;
typedef __attribute__((ext_vector_type(4))) float f32x4;
typedef __attribute__((ext_vector_type(4))) unsigned short us4;

__device__ __forceinline__ unsigned short f2bf(float f) {
    unsigned u = __float_as_uint(f);
    u += 0x7FFFu + ((u >> 16) & 1u);   // RNE
    return (unsigned short)(u >> 16);
}

__device__ __forceinline__ void gload16(const void* g, void* l) {
    __builtin_amdgcn_global_load_lds(
        (const __attribute__((address_space(1))) unsigned int*)g,
        (__attribute__((address_space(3))) unsigned int*)l,
        16, 0, 0);
}

// ---------- kernel 1: fp32 -> bf16 (x) ----------
__global__ void cvt_f32_bf16(const float* __restrict__ in, unsigned short* __restrict__ out, int n4) {
    int i = blockIdx.x * blockDim.x + threadIdx.x;
    if (i >= n4) return;
    float4 v = ((const float4*)in)[i];
    us4 r = { f2bf(v.x), f2bf(v.y), f2bf(v.z), f2bf(v.w) };
    ((us4*)out)[i] = r;
}

// ---------- kernel 2: transpose + convert: in[R][C] f32 -> out[C][R] bf16 ----------
__global__ void tcvt(const float* __restrict__ in, unsigned short* __restrict__ out, int R, int C) {
    __shared__ float tile[32][33];
    int tx = threadIdx.x & 31, ty = threadIdx.x >> 5;  // 256 threads
    int c0 = blockIdx.x * 32, r0 = blockIdx.y * 32;
    #pragma unroll
    for (int i = 0; i < 32; i += 8)
        tile[ty + i][tx] = in[(size_t)(r0 + ty + i) * C + c0 + tx];
    __syncthreads();
    #pragma unroll
    for (int i = 0; i < 32; i += 8)
        out[(size_t)(c0 + ty + i) * R + r0 + tx] = f2bf(tile[tx][ty + i]);
}

// ---------- 256x256 8-phase GEMM (B^T input), BK=64 (2x 32-k panels), 512 thr ----------
#define MF(af, bf, fi, ni) acc[fi][ni] = __builtin_amdgcn_mfma_f32_16x16x32_bf16(af, bf, acc[fi][ni], 0, 0, 0)
#define LOADA(p, off) do { a0 = *(const bf16x8*)((p)+(off)); a1 = *(const bf16x8*)((p)+(off)+1024); \
                           a2 = *(const bf16x8*)((p)+(off)+2048); a3 = *(const bf16x8*)((p)+(off)+3072); } while(0)
#define LOADB(p) do { b0 = *(const bf16x8*)(p); b1 = *(const bf16x8*)((p)+1024); \
                      b2 = *(const bf16x8*)((p)+2048); b3 = *(const bf16x8*)((p)+3072); } while(0)
#define MFMA16(base) do { \
    MF(a0,b0,(base)+0,0); MF(a0,b1,(base)+0,1); MF(a0,b2,(base)+0,2); MF(a0,b3,(base)+0,3); \
    MF(a1,b0,(base)+1,0); MF(a1,b1,(base)+1,1); MF(a1,b2,(base)+1,2); MF(a1,b3,(base)+1,3); \
    MF(a2,b0,(base)+2,0); MF(a2,b1,(base)+2,1); MF(a2,b2,(base)+2,2); MF(a2,b3,(base)+2,3); \
    MF(a3,b0,(base)+3,0); MF(a3,b1,(base)+3,1); MF(a3,b2,(base)+3,2); MF(a3,b3,(base)+3,3); } while(0)
#define STG(gb, lp, buf, kkk, kt) do { \
    size_t ko = (size_t)(kt) * 128 + (kkk) * 64; \
    char* lpp = (lp) + (buf) * 32768 + (kkk) * 16384; \
    gload16((gb) + sR0 + ko, lpp + dst0); \
    gload16((gb) + sR1 + ko, lpp + dst1); } while (0)

template <int MODE>
__global__ __launch_bounds__(512) void gemm8p(
    const unsigned short* __restrict__ A, const unsigned short* __restrict__ Bt,
    int M, int N, int K, float* __restrict__ Cf,
    unsigned short* __restrict__ qp, unsigned short* __restrict__ kp,
    unsigned short* __restrict__ vTp,
    const float* __restrict__ ropeC, const float* __restrict__ ropeS)
{
    __shared__ unsigned short lA[2][2][8192];   // 64 KB
    __shared__ unsigned short lB[2][2][8192];   // 64 KB
    const int tid = threadIdx.x;
    const int lane = tid & 63, wid = tid >> 6;
    const int ln15 = lane & 15, hig = lane >> 4;
    const int wr = wid >> 2, wc = wid & 3;

    int nwg = gridDim.x * gridDim.y;
    int flat = blockIdx.y * gridDim.x + blockIdx.x;
    int swz = ((nwg & 7) == 0) ? ((flat & 7) * (nwg >> 3) + (flat >> 3)) : flat;
    const int bx = swz % gridDim.x, by = swz / gridDim.x;
    const int mbase = by * 256, nbase = bx * 256;
    const size_t Kb = (size_t)K * 2;

    const char* Ag = (const char*)A + (size_t)mbase * Kb;
    const char* Bg = (const char*)Bt + (size_t)nbase * Kb;
    char* lAc = (char*)&lA[0][0][0];
    char* lBc = (char*)&lB[0][0][0];

    const int srow = tid >> 2;
    const int gsrc = (tid & 3) ^ (((tid >> 5) & 1) << 1);   // inverse-swizzled k-group
    const size_t sR0 = (size_t)srow * Kb + gsrc * 16;
    const size_t sR1 = (size_t)(srow + 128) * Kb + gsrc * 16;
    const int dst0 = tid * 16, dst1 = (tid + 512) * 16;

    const int colOff = (hig * 16) ^ (((ln15 >> 3) & 1) << 5);
    const int aRow = (wr * 128 + ln15) * 64 + colOff;
    const int bRow = (wc * 64 + ln15) * 64 + colOff;

    f32x4 acc[8][4] = {};
    const int T = K >> 6;

    STG(Ag, lAc, 0, 0, 0);
    STG(Bg, lBc, 0, 0, 0);
    STG(Ag, lAc, 0, 1, 0);
    STG(Bg, lBc, 0, 1, 0);
    STG(Ag, lAc, 1, 0, 1);
    STG(Bg, lBc, 1, 0, 1);
    asm volatile("s_waitcnt vmcnt(8)" ::: "memory");
    __builtin_amdgcn_s_barrier();

    for (int t = 0; t < T; t++) {
        const int cur = t & 1, nxt = cur ^ 1;
        const char* pa0 = lAc + cur * 32768 + aRow;
        const char* pb0 = lBc + cur * 32768 + bRow;
        const char* pa1 = pa0 + 16384;
        const char* pb1 = pb0 + 16384;
        const bool tail = (t >= T - 2);
        bf16x8 a0, a1, a2, a3, b0, b1, b2, b3;

        LOADA(pa0, 0);
        LOADB(pb0);
        if (t + 1 < T) STG(Ag, lAc, nxt, 1, t + 1);
        __builtin_amdgcn_s_barrier();
        __builtin_amdgcn_s_setprio(1);
        MFMA16(0);
        __builtin_amdgcn_s_setprio(0);
        __builtin_amdgcn_s_barrier();

        LOADA(pa0, 4096);
        if (t + 1 < T) STG(Bg, lBc, nxt, 1, t + 1);
        if (tail) asm volatile("s_waitcnt vmcnt(0)" ::: "memory");
        else      asm volatile("s_waitcnt vmcnt(6)" ::: "memory");
        __builtin_amdgcn_s_barrier();
        __builtin_amdgcn_s_setprio(1);
        MFMA16(4);
        __builtin_amdgcn_s_setprio(0);
        __builtin_amdgcn_s_barrier();

        LOADA(pa1, 0);
        LOADB(pb1);
        if (t + 2 < T) STG(Ag, lAc, cur, 0, t + 2);
        __builtin_amdgcn_s_barrier();
        __builtin_amdgcn_s_setprio(1);
        MFMA16(0);
        __builtin_amdgcn_s_setprio(0);
        __builtin_amdgcn_s_barrier();

        LOADA(pa1, 4096);
        if (t + 2 < T) STG(Bg, lBc, cur, 0, t + 2);
        if (tail) asm volatile("s_waitcnt vmcnt(0)" ::: "memory");
        else      asm volatile("s_waitcnt vmcnt(6)" ::: "memory");
        __builtin_amdgcn_s_barrier();
        __builtin_amdgcn_s_setprio(1);
        MFMA16(4);
        __builtin_amdgcn_s_setprio(0);
        __builtin_amdgcn_s_barrier();
    }

    if (MODE == 0) {
        #pragma unroll
        for (int fg = 0; fg < 8; fg++)
            #pragma unroll
            for (int n = 0; n < 4; n++)
                #pragma unroll
                for (int j = 0; j < 4; j++) {
                    int m = mbase + wr * 128 + fg * 16 + hig * 4 + j;
                    int col = nbase + wc * 64 + n * 16 + ln15;
                    Cf[(size_t)m * N + col] = acc[fg][n][j];
                }
    } else {
        const int colb = nbase + wc * 64;
        const int sec = colb >> 11;               // 0=q, 1=k, 2=v
        if (sec < 2) {
            unsigned short* dst = (sec == 0) ? qp : kp;
            const float scale = (sec == 0) ? 0.08838834764831845f : 1.0f;
            #pragma unroll
            for (int fg = 0; fg < 8; fg++)
                #pragma unroll
                for (int n = 0; n < 4; n++) {
                    int within = (colb & 2047) + n * 16 + ln15;
                    int h = within >> 7, d = within & 127, pidx = d >> 1;
                    #pragma unroll
                    for (int j = 0; j < 4; j++) {
                        int m = mbase + wr * 128 + fg * 16 + hig * 4 + j;
                        int b = m >> 11, tq = m & 2047;
                        float v = acc[fg][n][j];
                        float pv = __shfl_xor(v, 1);
                        float c = ropeC[tq * 64 + pidx], s = ropeS[tq * 64 + pidx];
                        float o = (d & 1) ? fmaf(pv, s, v * c) : fmaf(-pv, s, v * c);
                        o *= scale;
                        dst[((size_t)((b << 4) + h) * 2048 + tq) * 128 + d] = f2bf(o);
                    }
                }
        } else {
            #pragma unroll
            for (int fg = 0; fg < 8; fg++)
                #pragma unroll
                for (int n = 0; n < 4; n++) {
                    int within = (colb & 2047) + n * 16 + ln15;
                    int h = within >> 7, d = within & 127;
                    int m0 = mbase + wr * 128 + fg * 16 + hig * 4;
                    int b = m0 >> 11, t0 = m0 & 2047;
                    us4 pk = { f2bf(acc[fg][n][0]), f2bf(acc[fg][n][1]),
                               f2bf(acc[fg][n][2]), f2bf(acc[fg][n][3]) };
                    *(us4*)(vTp + ((size_t)((b << 4) + h) * 128 + d) * 2048 + t0) = pk;
                }
        }
    }
}

// ---------- flash attention, causal, paired q-tiles, double-buffered K/V ----------
// grid: (64, 8)  x = bh (XCD locality: XCD = bh%8 shares K/V), y = q-pair
__global__ __launch_bounds__(256) void attn_fwd(
    const unsigned short* __restrict__ q, const unsigned short* __restrict__ k,
    const unsigned short* __restrict__ vT, unsigned short* __restrict__ outp)
{
    __shared__ unsigned short lK[2][64 * 128];   // 2 x 16 KB, XOR-swizzled rows (256B)
    __shared__ unsigned short lV[2][128 * 64];   // 2 x 16 KB, XOR-swizzled rows (128B)
    __shared__ unsigned short lP[4 * 32 * 64];   // 16 KB
    const int tid = threadIdx.x;
    const int lane = tid & 63, wid = tid >> 6;
    const int ln15 = lane & 15, hig = lane >> 4, hi8 = hig * 8;
    const int bh = blockIdx.x;

    const char* qg = (const char*)(q + (size_t)bh * 2048 * 128);
    const char* kg = (const char*)(k + (size_t)bh * 2048 * 128);
    const char* vg = (const char*)(vT + (size_t)bh * 128 * 2048);
    char* lKc = (char*)&lK[0][0];
    char* lVc = (char*)&lV[0][0];
    char* lPc = (char*)lP + wid * (32 * 64 * 2);
    const int b = bh >> 4, h = bh & 15;

    for (int rep = 0; rep < 2; rep++) {
        const int qt = rep == 0 ? (int)blockIdx.y : 15 - (int)blockIdx.y;
        const int qbase = qt * 128;
        const int qw = qbase + wid * 32;

        bf16x8 qf[2][4];
        #pragma unroll
        for (int mt = 0; mt < 2; mt++)
            #pragma unroll
            for (int ks = 0; ks < 4; ks++)
                qf[mt][ks] = *(const bf16x8*)(qg + ((size_t)(qw + mt * 16 + ln15) * 128 + ks * 32 + hi8) * 2);

        f32x4 o[2][8] = {};
        float mreg[2][4], lreg[2][4];
        #pragma unroll
        for (int mt = 0; mt < 2; mt++)
            #pragma unroll
            for (int j = 0; j < 4; j++) { mreg[mt][j] = -1e30f; lreg[mt][j] = 0.f; }

        // stage helper: one K tile (64x256B) + one V tile (128x128B) into buffer `bf`
        auto stageKV = [&](int bf, int kv0) {
            #pragma unroll
            for (int i = 0; i < 4; i++) {
                int slot = tid + i * 256;
                int row = slot >> 4, c = (slot & 15) * 16;
                gload16(kg + (size_t)(kv0 + row) * 256 + (c ^ ((row & 7) << 4)),
                        lKc + bf * 16384 + slot * 16);
            }
            #pragma unroll
            for (int i = 0; i < 4; i++) {
                int slot = tid + i * 256;
                int d = slot >> 3, c = (slot & 7) * 16;
                gload16(vg + (size_t)d * 4096 + (size_t)kv0 * 2 + (c ^ ((d & 7) << 4)),
                        lVc + bf * 16384 + slot * 16);
            }
        };

        const int ntiles = (qbase >> 6) + 2;
        // prologue: stage tile 0 into buf 0
        stageKV(0, 0);
        asm volatile("s_waitcnt vmcnt(0)" ::: "memory");
        __builtin_amdgcn_s_barrier();

        int buf = 0;
        for (int it = 0; it < ntiles; it++) {
            const int kv0 = it * 64;
            if (it + 1 < ntiles) stageKV(buf ^ 1, kv0 + 64);   // prefetch next tile

            if (kv0 <= qw + 31) {   // wave-active (causal range)
                const char* lKb = lKc + buf * 16384;
                const char* lVb = lVc + buf * 16384;

                f32x4 s[2][4] = {};
                #pragma unroll
                for (int ks = 0; ks < 4; ks++) {
                    bf16x8 kf[4];
                    #pragma unroll
                    for (int nt = 0; nt < 4; nt++) {
                        int row = nt * 16 + ln15;
                        kf[nt] = *(const bf16x8*)(lKb + row * 256 + (((ks * 32 + hi8) * 2) ^ ((row & 7) << 4)));
                    }
                    __builtin_amdgcn_s_setprio(1);
                    #pragma unroll
                    for (int mt = 0; mt < 2; mt++)
                        #pragma unroll
                        for (int nt = 0; nt < 4; nt++)
                            s[mt][nt] = __builtin_amdgcn_mfma_f32_16x16x32_bf16(qf[mt][ks], kf[nt], s[mt][nt], 0, 0, 0);
                    __builtin_amdgcn_s_setprio(0);
                }

                if (kv0 + 63 > qw) {  // diagonal tile needs masking
                    #pragma unroll
                    for (int mt = 0; mt < 2; mt++)
                        #pragma unroll
                        for (int nt = 0; nt < 4; nt++)
                            #pragma unroll
                            for (int j = 0; j < 4; j++) {
                                int qi = qw + mt * 16 + hig * 4 + j;
                                int kvi = kv0 + nt * 16 + ln15;
                                if (kvi > qi) s[mt][nt][j] = -1e30f;
                            }
                }

                // row max (4-bit shfl tree over 16 lanes)
                float vmax[2][4];
                #pragma unroll
                for (int mt = 0; mt < 2; mt++)
                    #pragma unroll
                    for (int j = 0; j < 4; j++) {
                        float v = fmaxf(fmaxf(s[mt][0][j], s[mt][1][j]), fmaxf(s[mt][2][j], s[mt][3][j]));
                        v = fmaxf(v, __shfl_xor(v, 1));
                        v = fmaxf(v, __shfl_xor(v, 2));
                        v = fmaxf(v, __shfl_xor(v, 4));
                        v = fmaxf(v, __shfl_xor(v, 8));
                        vmax[mt][j] = v;
                    }
                // defer-max: only rescale when some row max grew past threshold
                bool grow = false;
                #pragma unroll
                for (int mt = 0; mt < 2; mt++)
                    #pragma unroll
                    for (int j = 0; j < 4; j++)
                        grow = grow || (vmax[mt][j] > mreg[mt][j] + 8.0f);
                if (__any(grow)) {
                    #pragma unroll
                    for (int mt = 0; mt < 2; mt++)
                        #pragma unroll
                        for (int j = 0; j < 4; j++) {
                            float mn = fmaxf(mreg[mt][j], vmax[mt][j]);
                            float sc = __expf(mreg[mt][j] - mn);
                            mreg[mt][j] = mn;
                            lreg[mt][j] *= sc;
                            #pragma unroll
                            for (int ntd = 0; ntd < 8; ntd++) o[mt][ntd][j] *= sc;
                        }
                }
                #pragma unroll
                for (int mt = 0; mt < 2; mt++)
                    #pragma unroll
                    for (int j = 0; j < 4; j++) {
                        float rs = 0.f;
                        #pragma unroll
                        for (int nt = 0; nt < 4; nt++) {
                            float p = __expf(s[mt][nt][j] - mreg[mt][j]);
                            s[mt][nt][j] = p;
                            rs += p;
                        }
                        rs += __shfl_xor(rs, 1);
                        rs += __shfl_xor(rs, 2);
                        rs += __shfl_xor(rs, 4);
                        rs += __shfl_xor(rs, 8);
                        lreg[mt][j] += rs;
                    }

                // P -> per-wave LDS (bf16, swizzled), then re-fragment for PV
                #pragma unroll
                for (int mt = 0; mt < 2; mt++)
                    #pragma unroll
                    for (int nt = 0; nt < 4; nt++)
                        #pragma unroll
                        for (int j = 0; j < 4; j++) {
                            int row = mt * 16 + hig * 4 + j;
                            int addr = row * 128 + (((nt * 16 + ln15) * 2) ^ ((row & 7) << 4));
                            *(unsigned short*)(lPc + addr) = f2bf(s[mt][nt][j]);
                        }

                #pragma unroll
                for (int ks2 = 0; ks2 < 2; ks2++) {
                    bf16x8 pf[2];
                    #pragma unroll
                    for (int mt = 0; mt < 2; mt++) {
                        int row = mt * 16 + ln15;
                        pf[mt] = *(const bf16x8*)(lPc + row * 128 + (((ks2 * 32 + hi8) * 2) ^ ((row & 7) << 4)));
                    }
                    #pragma unroll
                    for (int ntd = 0; ntd < 8; ntd++) {
                        int drow = ntd * 16 + ln15;
                        bf16x8 vf = *(const bf16x8*)(lVb + drow * 128 + (((ks2 * 32 + hi8) * 2) ^ ((drow & 7) << 4)));
                        __builtin_amdgcn_s_setprio(1);
                        #pragma unroll
                        for (int mt = 0; mt < 2; mt++)
                            o[mt][ntd] = __builtin_amdgcn_mfma_f32_16x16x32_bf16(pf[mt], vf, o[mt][ntd], 0, 0, 0);
                        __builtin_amdgcn_s_setprio(0);
                    }
                }
            }

            asm volatile("s_waitcnt vmcnt(0)" ::: "memory");   // next tile staged
            __builtin_amdgcn_s_barrier();                       // all waves done with buf
            buf ^= 1;
        }

        #pragma unroll
        for (int mt = 0; mt < 2; mt++)
            #pragma unroll
            for (int j = 0; j < 4; j++) {
                float inv = 1.0f / lreg[mt][j];
                int t = qw + mt * 16 + hig * 4 + j;
                #pragma unroll
                for (int ntd = 0; ntd < 8; ntd++) {
                    int d = ntd * 16 + ln15;
                    outp[((size_t)b * 2048 + t) * 2048 + h * 128 + d] = f2bf(o[mt][ntd][j] * inv);
                }
            }
    }
}

// ---------- launcher ----------
extern "C" void kernel_launch(void* const* d_in, const int* in_sizes, int n_in,
                              void* d_out, int out_size, void* d_ws, size_t ws_size,
                              hipStream_t stream) {
    const float* x     = (const float*)d_in[0];
    const float* wqkv  = (const float*)d_in[1];
    const float* wo    = (const float*)d_in[2];
    const float* ropeC = (const float*)d_in[3];
    const float* ropeS = (const float*)d_in[4];
    float* out = (float*)d_out;
    char* ws = (char*)d_ws;
    const size_t MB = 1024 * 1024;
    unsigned short* xb    = (unsigned short*)(ws);                  // 32 MB
    unsigned short* wqkvT = (unsigned short*)(ws + 32 * MB);        // 24 MB
    unsigned short* woT   = (unsigned short*)(ws + 56 * MB);        // 8 MB
    unsigned short* qb    = (unsigned short*)(ws + 64 * MB);        // 32 MB
    unsigned short* kb    = (unsigned short*)(ws + 96 * MB);        // 32 MB
    unsigned short* vTb   = (unsigned short*)(ws + 128 * MB);       // 32 MB
    unsigned short* attnb = (unsigned short*)(ws + 160 * MB);       // 32 MB

    cvt_f32_bf16<<<16384, 256, 0, stream>>>(x, xb, 4194304);
    tcvt<<<dim3(192, 64), 256, 0, stream>>>(wqkv, wqkvT, 2048, 6144);
    tcvt<<<dim3(64, 64), 256, 0, stream>>>(wo, woT, 2048, 2048);
    gemm8p<1><<<dim3(24, 32), 512, 0, stream>>>(xb, wqkvT, 8192, 6144, 2048,
                                                nullptr, qb, kb, vTb, ropeC, ropeS);
    attn_fwd<<<dim3(64, 8), 256, 0, stream>>>(qb, kb, vTb, attnb);
    gemm8p<0><<<dim3(8, 32), 512, 0, stream>>>(attnb, woT, 8192, 2048, 2048,
                                               out, nullptr, nullptr, nullptr, nullptr, nullptr);
}

// Round 5
// 531.082 us; speedup vs baseline: 1.6287x; 1.0578x over previous
//
#include <hip/hip_runtime.h>
#include <hip/hip_bf16.h>

// ---------- types ----------
typedef __attribute__((ext_vector_type(8))) __bf16 bf16x8;
typedef __attribute__((ext_vector_type(4))) float f32x4;
typedef __attribute__((ext_vector_type(4))) unsigned short us4;

__device__ __forceinline__ unsigned short f2bf(float f) {
    unsigned u = __float_as_uint(f);
    u += 0x7FFFu + ((u >> 16) & 1u);   // RNE
    return (unsigned short)(u >> 16);
}

__device__ __forceinline__ void gload16(const void* g, void* l) {
    __builtin_amdgcn_global_load_lds(
        (const __attribute__((address_space(1))) unsigned int*)g,
        (__attribute__((address_space(3))) unsigned int*)l,
        16, 0, 0);
}

// ---------- kernel 1: fp32 -> bf16 (x) ----------
__global__ void cvt_f32_bf16(const float* __restrict__ in, unsigned short* __restrict__ out, int n4) {
    int i = blockIdx.x * blockDim.x + threadIdx.x;
    if (i >= n4) return;
    float4 v = ((const float4*)in)[i];
    us4 r = { f2bf(v.x), f2bf(v.y), f2bf(v.z), f2bf(v.w) };
    ((us4*)out)[i] = r;
}

// ---------- kernel 2: transpose + convert: in[R][C] f32 -> out[C][R] bf16 ----------
__global__ void tcvt(const float* __restrict__ in, unsigned short* __restrict__ out, int R, int C) {
    __shared__ float tile[32][33];
    int tx = threadIdx.x & 31, ty = threadIdx.x >> 5;  // 256 threads
    int c0 = blockIdx.x * 32, r0 = blockIdx.y * 32;
    #pragma unroll
    for (int i = 0; i < 32; i += 8)
        tile[ty + i][tx] = in[(size_t)(r0 + ty + i) * C + c0 + tx];
    __syncthreads();
    #pragma unroll
    for (int i = 0; i < 32; i += 8)
        out[(size_t)(c0 + ty + i) * R + r0 + tx] = f2bf(tile[tx][ty + i]);
}

// ---------- 256x256 8-phase GEMM (B^T input), BK=64 (2x 32-k panels), 512 thr ----------
#define MF(af, bf, fi, ni) acc[fi][ni] = __builtin_amdgcn_mfma_f32_16x16x32_bf16(af, bf, acc[fi][ni], 0, 0, 0)
#define LOADA(p, off) do { a0 = *(const bf16x8*)((p)+(off)); a1 = *(const bf16x8*)((p)+(off)+1024); \
                           a2 = *(const bf16x8*)((p)+(off)+2048); a3 = *(const bf16x8*)((p)+(off)+3072); } while(0)
#define LOADB(p) do { b0 = *(const bf16x8*)(p); b1 = *(const bf16x8*)((p)+1024); \
                      b2 = *(const bf16x8*)((p)+2048); b3 = *(const bf16x8*)((p)+3072); } while(0)
#define MFMA16(base) do { \
    MF(a0,b0,(base)+0,0); MF(a0,b1,(base)+0,1); MF(a0,b2,(base)+0,2); MF(a0,b3,(base)+0,3); \
    MF(a1,b0,(base)+1,0); MF(a1,b1,(base)+1,1); MF(a1,b2,(base)+1,2); MF(a1,b3,(base)+1,3); \
    MF(a2,b0,(base)+2,0); MF(a2,b1,(base)+2,1); MF(a2,b2,(base)+2,2); MF(a2,b3,(base)+2,3); \
    MF(a3,b0,(base)+3,0); MF(a3,b1,(base)+3,1); MF(a3,b2,(base)+3,2); MF(a3,b3,(base)+3,3); } while(0)
#define STG(gb, lp, buf, kkk, kt) do { \
    size_t ko = (size_t)(kt) * 128 + (kkk) * 64; \
    char* lpp = (lp) + (buf) * 32768 + (kkk) * 16384; \
    gload16((gb) + sR0 + ko, lpp + dst0); \
    gload16((gb) + sR1 + ko, lpp + dst1); } while (0)

template <int MODE>
__global__ __launch_bounds__(512) void gemm8p(
    const unsigned short* __restrict__ A, const unsigned short* __restrict__ Bt,
    int M, int N, int K, float* __restrict__ Cf,
    unsigned short* __restrict__ qp, unsigned short* __restrict__ kp,
    unsigned short* __restrict__ vTp,
    const float* __restrict__ ropeC, const float* __restrict__ ropeS)
{
    __shared__ unsigned short lA[2][2][8192];   // 64 KB
    __shared__ unsigned short lB[2][2][8192];   // 64 KB
    const int tid = threadIdx.x;
    const int lane = tid & 63, wid = tid >> 6;
    const int ln15 = lane & 15, hig = lane >> 4;
    const int wr = wid >> 2, wc = wid & 3;

    int nwg = gridDim.x * gridDim.y;
    int flat = blockIdx.y * gridDim.x + blockIdx.x;
    int swz = ((nwg & 7) == 0) ? ((flat & 7) * (nwg >> 3) + (flat >> 3)) : flat;
    const int bx = swz % gridDim.x, by = swz / gridDim.x;
    const int mbase = by * 256, nbase = bx * 256;
    const size_t Kb = (size_t)K * 2;

    const char* Ag = (const char*)A + (size_t)mbase * Kb;
    const char* Bg = (const char*)Bt + (size_t)nbase * Kb;
    char* lAc = (char*)&lA[0][0][0];
    char* lBc = (char*)&lB[0][0][0];

    const int srow = tid >> 2;
    const int gsrc = (tid & 3) ^ (((tid >> 5) & 1) << 1);   // inverse-swizzled k-group
    const size_t sR0 = (size_t)srow * Kb + gsrc * 16;
    const size_t sR1 = (size_t)(srow + 128) * Kb + gsrc * 16;
    const int dst0 = tid * 16, dst1 = (tid + 512) * 16;

    const int colOff = (hig * 16) ^ (((ln15 >> 3) & 1) << 5);
    const int aRow = (wr * 128 + ln15) * 64 + colOff;
    const int bRow = (wc * 64 + ln15) * 64 + colOff;

    f32x4 acc[8][4] = {};
    const int T = K >> 6;

    STG(Ag, lAc, 0, 0, 0);
    STG(Bg, lBc, 0, 0, 0);
    STG(Ag, lAc, 0, 1, 0);
    STG(Bg, lBc, 0, 1, 0);
    STG(Ag, lAc, 1, 0, 1);
    STG(Bg, lBc, 1, 0, 1);
    asm volatile("s_waitcnt vmcnt(8)" ::: "memory");
    __builtin_amdgcn_s_barrier();

    for (int t = 0; t < T; t++) {
        const int cur = t & 1, nxt = cur ^ 1;
        const char* pa0 = lAc + cur * 32768 + aRow;
        const char* pb0 = lBc + cur * 32768 + bRow;
        const char* pa1 = pa0 + 16384;
        const char* pb1 = pb0 + 16384;
        const bool tail = (t >= T - 2);
        bf16x8 a0, a1, a2, a3, b0, b1, b2, b3;

        LOADA(pa0, 0);
        LOADB(pb0);
        if (t + 1 < T) STG(Ag, lAc, nxt, 1, t + 1);
        __builtin_amdgcn_s_barrier();
        __builtin_amdgcn_s_setprio(1);
        MFMA16(0);
        __builtin_amdgcn_s_setprio(0);
        __builtin_amdgcn_s_barrier();

        LOADA(pa0, 4096);
        if (t + 1 < T) STG(Bg, lBc, nxt, 1, t + 1);
        if (tail) asm volatile("s_waitcnt vmcnt(0)" ::: "memory");
        else      asm volatile("s_waitcnt vmcnt(6)" ::: "memory");
        __builtin_amdgcn_s_barrier();
        __builtin_amdgcn_s_setprio(1);
        MFMA16(4);
        __builtin_amdgcn_s_setprio(0);
        __builtin_amdgcn_s_barrier();

        LOADA(pa1, 0);
        LOADB(pb1);
        if (t + 2 < T) STG(Ag, lAc, cur, 0, t + 2);
        __builtin_amdgcn_s_barrier();
        __builtin_amdgcn_s_setprio(1);
        MFMA16(0);
        __builtin_amdgcn_s_setprio(0);
        __builtin_amdgcn_s_barrier();

        LOADA(pa1, 4096);
        if (t + 2 < T) STG(Bg, lBc, cur, 0, t + 2);
        if (tail) asm volatile("s_waitcnt vmcnt(0)" ::: "memory");
        else      asm volatile("s_waitcnt vmcnt(6)" ::: "memory");
        __builtin_amdgcn_s_barrier();
        __builtin_amdgcn_s_setprio(1);
        MFMA16(4);
        __builtin_amdgcn_s_setprio(0);
        __builtin_amdgcn_s_barrier();
    }

    if (MODE == 0) {
        #pragma unroll
        for (int fg = 0; fg < 8; fg++)
            #pragma unroll
            for (int n = 0; n < 4; n++)
                #pragma unroll
                for (int j = 0; j < 4; j++) {
                    int m = mbase + wr * 128 + fg * 16 + hig * 4 + j;
                    int col = nbase + wc * 64 + n * 16 + ln15;
                    Cf[(size_t)m * N + col] = acc[fg][n][j];
                }
    } else {
        const int colb = nbase + wc * 64;
        const int sec = colb >> 11;               // 0=q, 1=k, 2=v
        if (sec < 2) {
            unsigned short* dst = (sec == 0) ? qp : kp;
            const float scale = (sec == 0) ? 0.08838834764831845f : 1.0f;
            #pragma unroll
            for (int fg = 0; fg < 8; fg++)
                #pragma unroll
                for (int n = 0; n < 4; n++) {
                    int within = (colb & 2047) + n * 16 + ln15;
                    int h = within >> 7, d = within & 127, pidx = d >> 1;
                    #pragma unroll
                    for (int j = 0; j < 4; j++) {
                        int m = mbase + wr * 128 + fg * 16 + hig * 4 + j;
                        int b = m >> 11, tq = m & 2047;
                        float v = acc[fg][n][j];
                        float pv = __shfl_xor(v, 1);
                        float c = ropeC[tq * 64 + pidx], s = ropeS[tq * 64 + pidx];
                        float o = (d & 1) ? fmaf(pv, s, v * c) : fmaf(-pv, s, v * c);
                        o *= scale;
                        dst[((size_t)((b << 4) + h) * 2048 + tq) * 128 + d] = f2bf(o);
                    }
                }
        } else {
            #pragma unroll
            for (int fg = 0; fg < 8; fg++)
                #pragma unroll
                for (int n = 0; n < 4; n++) {
                    int within = (colb & 2047) + n * 16 + ln15;
                    int h = within >> 7, d = within & 127;
                    int m0 = mbase + wr * 128 + fg * 16 + hig * 4;
                    int b = m0 >> 11, t0 = m0 & 2047;
                    us4 pk = { f2bf(acc[fg][n][0]), f2bf(acc[fg][n][1]),
                               f2bf(acc[fg][n][2]), f2bf(acc[fg][n][3]) };
                    *(us4*)(vTp + ((size_t)((b << 4) + h) * 128 + d) * 2048 + t0) = pk;
                }
        }
    }
}

// ---------- flash attention, causal, swapped QK^T (lane-local softmax rows) ----------
// grid: (64, 8)  x = bh (XCD locality), y = q-pair.  q,k: [BH][T][D] (q pre-scaled); vT: [BH][D][T]
// Swapped MFMA: s = mfma(K_frag, Q_frag) -> s[mt][nt]: q = qw+mt*16+ln15, kv = kv0+nt*16+4*hig+j.
// Row softmax: 15 in-lane fmax + 2 shfl (vs 64 shfl unswapped). P-write: 8x ds_write_b64.
__global__ __launch_bounds__(256, 3) void attn_fwd(
    const unsigned short* __restrict__ q, const unsigned short* __restrict__ k,
    const unsigned short* __restrict__ vT, unsigned short* __restrict__ outp)
{
    __shared__ unsigned short lK[64 * 128];   // 16 KB, [kv][d], XOR-swizzled rows (256B)
    __shared__ unsigned short lV[128 * 64];   // 16 KB, [d][kv], XOR-swizzled rows (128B)
    __shared__ unsigned short lP[4 * 32 * 64];// 16 KB, per-wave
    const int tid = threadIdx.x;
    const int lane = tid & 63, wid = tid >> 6;
    const int ln15 = lane & 15, hig = lane >> 4, hi8 = hig * 8;
    const int bh = blockIdx.x;

    const char* qg = (const char*)(q + (size_t)bh * 2048 * 128);
    const char* kg = (const char*)(k + (size_t)bh * 2048 * 128);
    const char* vg = (const char*)(vT + (size_t)bh * 128 * 2048);
    char* lKc = (char*)lK;
    char* lVc = (char*)lV;
    char* lPc = (char*)lP + wid * (32 * 64 * 2);
    const int b = bh >> 4, h = bh & 15;

    for (int rep = 0; rep < 2; rep++) {
        const int qt = rep == 0 ? (int)blockIdx.y : 15 - (int)blockIdx.y;
        const int qbase = qt * 128;
        const int qw = qbase + wid * 32;

        bf16x8 qf[2][4];
        #pragma unroll
        for (int mt = 0; mt < 2; mt++)
            #pragma unroll
            for (int ks = 0; ks < 4; ks++)
                qf[mt][ks] = *(const bf16x8*)(qg + ((size_t)(qw + mt * 16 + ln15) * 128 + ks * 32 + hi8) * 2);

        f32x4 o[2][8] = {};
        float mreg[2] = { -1e30f, -1e30f };
        float lreg[2] = { 0.f, 0.f };

        const int ntiles = (qbase >> 6) + 2;
        for (int it = 0; it < ntiles; it++) {
            const int kv0 = it * 64;
            // stage K tile (64x256B) + V tile (128x128B)
            #pragma unroll
            for (int i = 0; i < 4; i++) {
                int slot = tid + i * 256;
                int row = slot >> 4, c = (slot & 15) * 16;
                gload16(kg + (size_t)(kv0 + row) * 256 + (c ^ ((row & 7) << 4)), lKc + slot * 16);
            }
            #pragma unroll
            for (int i = 0; i < 4; i++) {
                int slot = tid + i * 256;
                int d = slot >> 3, c = (slot & 7) * 16;
                gload16(vg + (size_t)d * 4096 + (size_t)kv0 * 2 + (c ^ ((d & 7) << 4)), lVc + slot * 16);
            }
            asm volatile("s_waitcnt vmcnt(0)" ::: "memory");
            __builtin_amdgcn_s_barrier();

            if (kv0 <= qw + 31) {   // wave-active (causal range)
                f32x4 s[2][4] = {};
                #pragma unroll
                for (int ks = 0; ks < 4; ks++) {
                    bf16x8 kf[4];
                    #pragma unroll
                    for (int nt = 0; nt < 4; nt++) {
                        int row = nt * 16 + ln15;
                        kf[nt] = *(const bf16x8*)(lKc + row * 256 + (((ks * 32 + hi8) * 2) ^ ((row & 7) << 4)));
                    }
                    __builtin_amdgcn_s_setprio(1);
                    #pragma unroll
                    for (int mt = 0; mt < 2; mt++)
                        #pragma unroll
                        for (int nt = 0; nt < 4; nt++)
                            s[mt][nt] = __builtin_amdgcn_mfma_f32_16x16x32_bf16(kf[nt], qf[mt][ks], s[mt][nt], 0, 0, 0);
                    __builtin_amdgcn_s_setprio(0);
                }

                if (kv0 + 63 > qw) {  // diagonal tile: mask kv > q
                    #pragma unroll
                    for (int mt = 0; mt < 2; mt++) {
                        int qi = qw + mt * 16 + ln15;
                        #pragma unroll
                        for (int nt = 0; nt < 4; nt++)
                            #pragma unroll
                            for (int j = 0; j < 4; j++) {
                                int kvi = kv0 + nt * 16 + 4 * hig + j;
                                if (kvi > qi) s[mt][nt][j] = -1e30f;
                            }
                    }
                }

                // per-lane row max: 16 in-lane values + cross-hig shfl
                float vmax[2];
                #pragma unroll
                for (int mt = 0; mt < 2; mt++) {
                    float v = fmaxf(fmaxf(s[mt][0][0], s[mt][0][1]), fmaxf(s[mt][0][2], s[mt][0][3]));
                    #pragma unroll
                    for (int nt = 1; nt < 4; nt++)
                        v = fmaxf(v, fmaxf(fmaxf(s[mt][nt][0], s[mt][nt][1]), fmaxf(s[mt][nt][2], s[mt][nt][3])));
                    v = fmaxf(v, __shfl_xor(v, 16));
                    v = fmaxf(v, __shfl_xor(v, 32));
                    vmax[mt] = v;
                }
                // defer-max: rescale only when a row max grows past threshold
                bool grow = (vmax[0] > mreg[0] + 8.0f) || (vmax[1] > mreg[1] + 8.0f);
                if (__any(grow)) {
                    float sc[2];
                    #pragma unroll
                    for (int mt = 0; mt < 2; mt++) {
                        float mn = fmaxf(mreg[mt], vmax[mt]);
                        sc[mt] = __expf(mreg[mt] - mn);
                        mreg[mt] = mn;
                        lreg[mt] *= sc[mt];
                    }
                    #pragma unroll
                    for (int mt = 0; mt < 2; mt++)
                        #pragma unroll
                        for (int j = 0; j < 4; j++) {
                            float scj = __shfl(sc[mt], 4 * hig + j);   // to o-layout (q = 4*hig+j)
                            #pragma unroll
                            for (int ntd = 0; ntd < 8; ntd++) o[mt][ntd][j] *= scj;
                        }
                }
                // exp + row sum (in-lane + cross-hig)
                #pragma unroll
                for (int mt = 0; mt < 2; mt++) {
                    float rs = 0.f;
                    #pragma unroll
                    for (int nt = 0; nt < 4; nt++)
                        #pragma unroll
                        for (int j = 0; j < 4; j++) {
                            float p = __expf(s[mt][nt][j] - mreg[mt]);
                            s[mt][nt][j] = p;
                            rs += p;
                        }
                    rs += __shfl_xor(rs, 16);
                    rs += __shfl_xor(rs, 32);
                    lreg[mt] += rs;
                }

                // P -> per-wave LDS: row(q) = mt*16+ln15, col(k) = nt*16+4*hig+{0..3} -> one b64 store
                #pragma unroll
                for (int mt = 0; mt < 2; mt++) {
                    int rr = mt * 16 + ln15;
                    int rx = (rr & 7) << 4;
                    #pragma unroll
                    for (int nt = 0; nt < 4; nt++) {
                        us4 pk = { f2bf(s[mt][nt][0]), f2bf(s[mt][nt][1]),
                                   f2bf(s[mt][nt][2]), f2bf(s[mt][nt][3]) };
                        int addr = rr * 128 + ((nt * 32 + hig * 8) ^ rx);
                        *(us4*)(lPc + addr) = pk;
                    }
                }

                // PV: o += P(A) x V(B)
                #pragma unroll
                for (int ks2 = 0; ks2 < 2; ks2++) {
                    bf16x8 pf[2];
                    #pragma unroll
                    for (int mt = 0; mt < 2; mt++) {
                        int row = mt * 16 + ln15;
                        pf[mt] = *(const bf16x8*)(lPc + row * 128 + (((ks2 * 32 + hi8) * 2) ^ ((row & 7) << 4)));
                    }
                    #pragma unroll
                    for (int ntd = 0; ntd < 8; ntd++) {
                        int drow = ntd * 16 + ln15;
                        bf16x8 vf = *(const bf16x8*)(lVc + drow * 128 + (((ks2 * 32 + hi8) * 2) ^ ((drow & 7) << 4)));
                        __builtin_amdgcn_s_setprio(1);
                        #pragma unroll
                        for (int mt = 0; mt < 2; mt++)
                            o[mt][ntd] = __builtin_amdgcn_mfma_f32_16x16x32_bf16(pf[mt], vf, o[mt][ntd], 0, 0, 0);
                        __builtin_amdgcn_s_setprio(0);
                    }
                }
            }

            __builtin_amdgcn_s_barrier();   // all waves done with lK/lV before next stage
        }

        // epilogue: o[mt][ntd][j] is q = qw+mt*16+4*hig+j, d = ntd*16+ln15; lreg is at q=ln15
        #pragma unroll
        for (int mt = 0; mt < 2; mt++)
            #pragma unroll
            for (int j = 0; j < 4; j++) {
                float inv = 1.0f / __shfl(lreg[mt], 4 * hig + j);
                int t = qw + mt * 16 + hig * 4 + j;
                #pragma unroll
                for (int ntd = 0; ntd < 8; ntd++) {
                    int d = ntd * 16 + ln15;
                    outp[((size_t)b * 2048 + t) * 2048 + h * 128 + d] = f2bf(o[mt][ntd][j] * inv);
                }
            }
    }
}

// ---------- launcher ----------
extern "C" void kernel_launch(void* const* d_in, const int* in_sizes, int n_in,
                              void* d_out, int out_size, void* d_ws, size_t ws_size,
                              hipStream_t stream) {
    const float* x     = (const float*)d_in[0];
    const float* wqkv  = (const float*)d_in[1];
    const float* wo    = (const float*)d_in[2];
    const float* ropeC = (const float*)d_in[3];
    const float* ropeS = (const float*)d_in[4];
    float* out = (float*)d_out;
    char* ws = (char*)d_ws;
    const size_t MB = 1024 * 1024;
    unsigned short* xb    = (unsigned short*)(ws);                  // 32 MB
    unsigned short* wqkvT = (unsigned short*)(ws + 32 * MB);        // 24 MB
    unsigned short* woT   = (unsigned short*)(ws + 56 * MB);        // 8 MB
    unsigned short* qb    = (unsigned short*)(ws + 64 * MB);        // 32 MB
    unsigned short* kb    = (unsigned short*)(ws + 96 * MB);        // 32 MB
    unsigned short* vTb   = (unsigned short*)(ws + 128 * MB);       // 32 MB
    unsigned short* attnb = (unsigned short*)(ws + 160 * MB);       // 32 MB

    cvt_f32_bf16<<<16384, 256, 0, stream>>>(x, xb, 4194304);
    tcvt<<<dim3(192, 64), 256, 0, stream>>>(wqkv, wqkvT, 2048, 6144);
    tcvt<<<dim3(64, 64), 256, 0, stream>>>(wo, woT, 2048, 2048);
    gemm8p<1><<<dim3(24, 32), 512, 0, stream>>>(xb, wqkvT, 8192, 6144, 2048,
                                                nullptr, qb, kb, vTb, ropeC, ropeS);
    attn_fwd<<<dim3(64, 8), 256, 0, stream>>>(qb, kb, vTb, attnb);
    gemm8p<0><<<dim3(8, 32), 512, 0, stream>>>(attnb, woT, 8192, 2048, 2048,
                                               out, nullptr, nullptr, nullptr, nullptr, nullptr);
}

// Round 6
// 434.214 us; speedup vs baseline: 1.9921x; 1.2231x over previous
//
#include <hip/hip_runtime.h>
#include <hip/hip_bf16.h>

// ---------- types ----------
typedef __attribute__((ext_vector_type(8))) __bf16 bf16x8;
typedef __attribute__((ext_vector_type(4))) float f32x4;
typedef __attribute__((ext_vector_type(4))) unsigned short us4;

__device__ __forceinline__ unsigned short f2bf(float f) {
    unsigned u = __float_as_uint(f);
    u += 0x7FFFu + ((u >> 16) & 1u);   // RNE
    return (unsigned short)(u >> 16);
}

__device__ __forceinline__ void gload16(const void* g, void* l) {
    __builtin_amdgcn_global_load_lds(
        (const __attribute__((address_space(1))) unsigned int*)g,
        (__attribute__((address_space(3))) unsigned int*)l,
        16, 0, 0);
}

// ---------- kernel 1: fp32 -> bf16 (x) ----------
__global__ void cvt_f32_bf16(const float* __restrict__ in, unsigned short* __restrict__ out, int n4) {
    int i = blockIdx.x * blockDim.x + threadIdx.x;
    if (i >= n4) return;
    float4 v = ((const float4*)in)[i];
    us4 r = { f2bf(v.x), f2bf(v.y), f2bf(v.z), f2bf(v.w) };
    ((us4*)out)[i] = r;
}

// ---------- kernel 2: transpose + convert: in[R][C] f32 -> out[C][R] bf16 ----------
__global__ void tcvt(const float* __restrict__ in, unsigned short* __restrict__ out, int R, int C) {
    __shared__ float tile[32][33];
    int tx = threadIdx.x & 31, ty = threadIdx.x >> 5;  // 256 threads
    int c0 = blockIdx.x * 32, r0 = blockIdx.y * 32;
    #pragma unroll
    for (int i = 0; i < 32; i += 8)
        tile[ty + i][tx] = in[(size_t)(r0 + ty + i) * C + c0 + tx];
    __syncthreads();
    #pragma unroll
    for (int i = 0; i < 32; i += 8)
        out[(size_t)(c0 + ty + i) * R + r0 + tx] = f2bf(tile[tx][ty + i]);
}

// ---------- 256x256 8-phase GEMM (B^T input), BK=64 (2x 32-k panels), 512 thr ----------
#define MF(af, bf, fi, ni) acc[fi][ni] = __builtin_amdgcn_mfma_f32_16x16x32_bf16(af, bf, acc[fi][ni], 0, 0, 0)
#define LOADA(p, off) do { a0 = *(const bf16x8*)((p)+(off)); a1 = *(const bf16x8*)((p)+(off)+1024); \
                           a2 = *(const bf16x8*)((p)+(off)+2048); a3 = *(const bf16x8*)((p)+(off)+3072); } while(0)
#define LOADB(p) do { b0 = *(const bf16x8*)(p); b1 = *(const bf16x8*)((p)+1024); \
                      b2 = *(const bf16x8*)((p)+2048); b3 = *(const bf16x8*)((p)+3072); } while(0)
#define MFMA16(base) do { \
    MF(a0,b0,(base)+0,0); MF(a0,b1,(base)+0,1); MF(a0,b2,(base)+0,2); MF(a0,b3,(base)+0,3); \
    MF(a1,b0,(base)+1,0); MF(a1,b1,(base)+1,1); MF(a1,b2,(base)+1,2); MF(a1,b3,(base)+1,3); \
    MF(a2,b0,(base)+2,0); MF(a2,b1,(base)+2,1); MF(a2,b2,(base)+2,2); MF(a2,b3,(base)+2,3); \
    MF(a3,b0,(base)+3,0); MF(a3,b1,(base)+3,1); MF(a3,b2,(base)+3,2); MF(a3,b3,(base)+3,3); } while(0)
#define STG(gb, lp, buf, kkk, kt) do { \
    size_t ko = (size_t)(kt) * 128 + (kkk) * 64; \
    char* lpp = (lp) + (buf) * 32768 + (kkk) * 16384; \
    gload16((gb) + sR0 + ko, lpp + dst0); \
    gload16((gb) + sR1 + ko, lpp + dst1); } while (0)
#define PHASE_SYNC() do { \
    __builtin_amdgcn_s_barrier(); \
    asm volatile("s_waitcnt lgkmcnt(0)" ::: "memory"); \
    __builtin_amdgcn_sched_barrier(0); } while (0)

template <int MODE>
__global__ __launch_bounds__(512) void gemm8p(
    const unsigned short* __restrict__ A, const unsigned short* __restrict__ Bt,
    int M, int N, int K, float* __restrict__ Cf,
    unsigned short* __restrict__ qp, unsigned short* __restrict__ kp,
    unsigned short* __restrict__ vTp,
    const float* __restrict__ ropeC, const float* __restrict__ ropeS,
    int cby, int cbx)
{
    __shared__ unsigned short lA[2][2][8192];   // 64 KB
    __shared__ unsigned short lB[2][2][8192];   // 64 KB
    const int tid = threadIdx.x;
    const int lane = tid & 63, wid = tid >> 6;
    const int ln15 = lane & 15, hig = lane >> 4;
    const int wr = wid >> 2, wc = wid & 3;

    // 2D-chunk XCD swizzle: 8 chunks of (cby x cbx) blocks, chunk = flat & 7
    int nwg = gridDim.x * gridDim.y;
    int flat = blockIdx.y * gridDim.x + blockIdx.x;
    int bx, by;
    if ((nwg & 7) == 0) {
        int c = flat & 7, local = flat >> 3;
        int chunkCols = gridDim.x / cbx;
        by = (c / chunkCols) * cby + local / cbx;
        bx = (c % chunkCols) * cbx + local % cbx;
    } else {
        bx = flat % gridDim.x; by = flat / gridDim.x;
    }
    const int mbase = by * 256, nbase = bx * 256;
    const size_t Kb = (size_t)K * 2;

    const char* Ag = (const char*)A + (size_t)mbase * Kb;
    const char* Bg = (const char*)Bt + (size_t)nbase * Kb;
    char* lAc = (char*)&lA[0][0][0];
    char* lBc = (char*)&lB[0][0][0];

    const int srow = tid >> 2;
    const int gsrc = (tid & 3) ^ (((tid >> 5) & 1) << 1);   // inverse-swizzled k-group
    const size_t sR0 = (size_t)srow * Kb + gsrc * 16;
    const size_t sR1 = (size_t)(srow + 128) * Kb + gsrc * 16;
    const int dst0 = tid * 16, dst1 = (tid + 512) * 16;

    const int colOff = (hig * 16) ^ (((ln15 >> 3) & 1) << 5);
    const int aRow = (wr * 128 + ln15) * 64 + colOff;
    const int bRow = (wc * 64 + ln15) * 64 + colOff;

    f32x4 acc[8][4] = {};
    const int T = K >> 6;

    STG(Ag, lAc, 0, 0, 0);
    STG(Bg, lBc, 0, 0, 0);
    STG(Ag, lAc, 0, 1, 0);
    STG(Bg, lBc, 0, 1, 0);
    STG(Ag, lAc, 1, 0, 1);
    STG(Bg, lBc, 1, 0, 1);
    asm volatile("s_waitcnt vmcnt(8)" ::: "memory");
    __builtin_amdgcn_s_barrier();

    for (int t = 0; t < T; t++) {
        const int cur = t & 1, nxt = cur ^ 1;
        const char* pa0 = lAc + cur * 32768 + aRow;
        const char* pb0 = lBc + cur * 32768 + bRow;
        const char* pa1 = pa0 + 16384;
        const char* pb1 = pb0 + 16384;
        const bool tail = (t >= T - 2);
        bf16x8 a0, a1, a2, a3, b0, b1, b2, b3;

        LOADA(pa0, 0);
        LOADB(pb0);
        if (t + 1 < T) STG(Ag, lAc, nxt, 1, t + 1);
        PHASE_SYNC();
        __builtin_amdgcn_s_setprio(1);
        MFMA16(0);
        __builtin_amdgcn_s_setprio(0);
        __builtin_amdgcn_s_barrier();

        LOADA(pa0, 4096);
        if (t + 1 < T) STG(Bg, lBc, nxt, 1, t + 1);
        if (tail) asm volatile("s_waitcnt vmcnt(0)" ::: "memory");
        else      asm volatile("s_waitcnt vmcnt(6)" ::: "memory");
        PHASE_SYNC();
        __builtin_amdgcn_s_setprio(1);
        MFMA16(4);
        __builtin_amdgcn_s_setprio(0);
        __builtin_amdgcn_s_barrier();

        LOADA(pa1, 0);
        LOADB(pb1);
        if (t + 2 < T) STG(Ag, lAc, cur, 0, t + 2);
        PHASE_SYNC();
        __builtin_amdgcn_s_setprio(1);
        MFMA16(0);
        __builtin_amdgcn_s_setprio(0);
        __builtin_amdgcn_s_barrier();

        LOADA(pa1, 4096);
        if (t + 2 < T) STG(Bg, lBc, cur, 0, t + 2);
        if (tail) asm volatile("s_waitcnt vmcnt(0)" ::: "memory");
        else      asm volatile("s_waitcnt vmcnt(6)" ::: "memory");
        PHASE_SYNC();
        __builtin_amdgcn_s_setprio(1);
        MFMA16(4);
        __builtin_amdgcn_s_setprio(0);
        __builtin_amdgcn_s_barrier();
    }

    if (MODE == 0) {
        #pragma unroll
        for (int fg = 0; fg < 8; fg++)
            #pragma unroll
            for (int n = 0; n < 4; n++)
                #pragma unroll
                for (int j = 0; j < 4; j++) {
                    int m = mbase + wr * 128 + fg * 16 + hig * 4 + j;
                    int col = nbase + wc * 64 + n * 16 + ln15;
                    Cf[(size_t)m * N + col] = acc[fg][n][j];
                }
    } else {
        const int colb = nbase + wc * 64;
        const int sec = colb >> 11;               // 0=q, 1=k, 2=v
        if (sec < 2) {
            unsigned short* dst = (sec == 0) ? qp : kp;
            const float scale = (sec == 0) ? 0.08838834764831845f : 1.0f;
            #pragma unroll
            for (int fg = 0; fg < 8; fg++)
                #pragma unroll
                for (int n = 0; n < 4; n++) {
                    int within = (colb & 2047) + n * 16 + ln15;
                    int h = within >> 7, d = within & 127, pidx = d >> 1;
                    #pragma unroll
                    for (int j = 0; j < 4; j++) {
                        int m = mbase + wr * 128 + fg * 16 + hig * 4 + j;
                        int b = m >> 11, tq = m & 2047;
                        float v = acc[fg][n][j];
                        float pv = __shfl_xor(v, 1);
                        float c = ropeC[tq * 64 + pidx], s = ropeS[tq * 64 + pidx];
                        float o = (d & 1) ? fmaf(pv, s, v * c) : fmaf(-pv, s, v * c);
                        o *= scale;
                        dst[((size_t)((b << 4) + h) * 2048 + tq) * 128 + d] = f2bf(o);
                    }
                }
        } else {
            #pragma unroll
            for (int fg = 0; fg < 8; fg++)
                #pragma unroll
                for (int n = 0; n < 4; n++) {
                    int within = (colb & 2047) + n * 16 + ln15;
                    int h = within >> 7, d = within & 127;
                    int m0 = mbase + wr * 128 + fg * 16 + hig * 4;
                    int b = m0 >> 11, t0 = m0 & 2047;
                    us4 pk = { f2bf(acc[fg][n][0]), f2bf(acc[fg][n][1]),
                               f2bf(acc[fg][n][2]), f2bf(acc[fg][n][3]) };
                    *(us4*)(vTp + ((size_t)((b << 4) + h) * 128 + d) * 2048 + t0) = pk;
                }
        }
    }
}

// ---------- flash attention, causal, swapped QK^T, K/V double-buffer, counted vmcnt ----------
// grid: (64, 8)  x = bh (XCD locality), y = q-pair.  q,k: [BH][T][D] (q pre-scaled); vT: [BH][D][T]
// Swapped MFMA: s[mt][nt]: q = qw+mt*16+ln15, kv = kv0+nt*16+4*hig+j.
// Pipeline: tile t+2 staged at end of iter t; steady-state wait = vmcnt(8) (never 0 until last).
__global__ __launch_bounds__(256, 2) void attn_fwd(
    const unsigned short* __restrict__ q, const unsigned short* __restrict__ k,
    const unsigned short* __restrict__ vT, unsigned short* __restrict__ outp)
{
    __shared__ unsigned short lK[2][64 * 128];   // 2 x 16 KB, [kv][d], XOR-swizzled rows (256B)
    __shared__ unsigned short lV[2][128 * 64];   // 2 x 16 KB, [d][kv], XOR-swizzled rows (128B)
    __shared__ unsigned short lP[4 * 32 * 64];   // 16 KB, per-wave
    const int tid = threadIdx.x;
    const int lane = tid & 63, wid = tid >> 6;
    const int ln15 = lane & 15, hig = lane >> 4, hi8 = hig * 8;
    const int bh = blockIdx.x;

    const char* qg = (const char*)(q + (size_t)bh * 2048 * 128);
    const char* kg = (const char*)(k + (size_t)bh * 2048 * 128);
    const char* vg = (const char*)(vT + (size_t)bh * 128 * 2048);
    char* lKc = (char*)&lK[0][0];
    char* lVc = (char*)&lV[0][0];
    char* lPc = (char*)lP + wid * (32 * 64 * 2);
    const int b = bh >> 4, h = bh & 15;

    for (int rep = 0; rep < 2; rep++) {
        const int qt = rep == 0 ? (int)blockIdx.y : 15 - (int)blockIdx.y;
        const int qbase = qt * 128;
        const int qw = qbase + wid * 32;

        bf16x8 qf[2][4];
        #pragma unroll
        for (int mt = 0; mt < 2; mt++)
            #pragma unroll
            for (int ks = 0; ks < 4; ks++)
                qf[mt][ks] = *(const bf16x8*)(qg + ((size_t)(qw + mt * 16 + ln15) * 128 + ks * 32 + hi8) * 2);

        f32x4 o[2][8] = {};
        float mreg[2] = { -1e30f, -1e30f };
        float lreg[2] = { 0.f, 0.f };

        // stage tile (K: 64x256B, V: 128x128B) into buffer bf.  8 loads per thread-call.
        auto stageKV = [&](int bf, int kv0) {
            #pragma unroll
            for (int i = 0; i < 4; i++) {
                int slot = tid + i * 256;
                int row = slot >> 4, c = (slot & 15) * 16;
                gload16(kg + (size_t)(kv0 + row) * 256 + (c ^ ((row & 7) << 4)),
                        lKc + bf * 16384 + slot * 16);
            }
            #pragma unroll
            for (int i = 0; i < 4; i++) {
                int slot = tid + i * 256;
                int d = slot >> 3, c = (slot & 7) * 16;
                gload16(vg + (size_t)d * 4096 + (size_t)kv0 * 2 + (c ^ ((d & 7) << 4)),
                        lVc + bf * 16384 + slot * 16);
            }
        };

        const int ntiles = (qbase >> 6) + 2;   // >= 2 always
        stageKV(0, 0);
        if (ntiles > 1) stageKV(1, 64);

        for (int it = 0; it < ntiles; it++) {
            const int kv0 = it * 64;
            const int buf = it & 1;
            // retire tile `it` (oldest 8 own loads); keep tile it+1 in flight
            if (it + 1 < ntiles) asm volatile("s_waitcnt vmcnt(8)" ::: "memory");
            else                 asm volatile("s_waitcnt vmcnt(0)" ::: "memory");
            __builtin_amdgcn_s_barrier();      // all waves' parts of tile `it` visible

            if (kv0 <= qw + 31) {   // wave-active (causal range)
                const char* lKb = lKc + buf * 16384;
                const char* lVb = lVc + buf * 16384;

                f32x4 s[2][4] = {};
                #pragma unroll
                for (int ks = 0; ks < 4; ks++) {
                    bf16x8 kf[4];
                    #pragma unroll
                    for (int nt = 0; nt < 4; nt++) {
                        int row = nt * 16 + ln15;
                        kf[nt] = *(const bf16x8*)(lKb + row * 256 + (((ks * 32 + hi8) * 2) ^ ((row & 7) << 4)));
                    }
                    __builtin_amdgcn_s_setprio(1);
                    #pragma unroll
                    for (int mt = 0; mt < 2; mt++)
                        #pragma unroll
                        for (int nt = 0; nt < 4; nt++)
                            s[mt][nt] = __builtin_amdgcn_mfma_f32_16x16x32_bf16(kf[nt], qf[mt][ks], s[mt][nt], 0, 0, 0);
                    __builtin_amdgcn_s_setprio(0);
                }

                if (kv0 + 63 > qw) {  // diagonal tile: mask kv > q
                    #pragma unroll
                    for (int mt = 0; mt < 2; mt++) {
                        int qi = qw + mt * 16 + ln15;
                        #pragma unroll
                        for (int nt = 0; nt < 4; nt++)
                            #pragma unroll
                            for (int j = 0; j < 4; j++) {
                                int kvi = kv0 + nt * 16 + 4 * hig + j;
                                if (kvi > qi) s[mt][nt][j] = -1e30f;
                            }
                    }
                }

                // per-lane row max (16 in-lane) + cross-hig shfl
                float vmax[2];
                #pragma unroll
                for (int mt = 0; mt < 2; mt++) {
                    float v = fmaxf(fmaxf(s[mt][0][0], s[mt][0][1]), fmaxf(s[mt][0][2], s[mt][0][3]));
                    #pragma unroll
                    for (int nt = 1; nt < 4; nt++)
                        v = fmaxf(v, fmaxf(fmaxf(s[mt][nt][0], s[mt][nt][1]), fmaxf(s[mt][nt][2], s[mt][nt][3])));
                    v = fmaxf(v, __shfl_xor(v, 16));
                    v = fmaxf(v, __shfl_xor(v, 32));
                    vmax[mt] = v;
                }
                // defer-max rescale
                bool grow = (vmax[0] > mreg[0] + 8.0f) || (vmax[1] > mreg[1] + 8.0f);
                if (__any(grow)) {
                    float sc[2];
                    #pragma unroll
                    for (int mt = 0; mt < 2; mt++) {
                        float mn = fmaxf(mreg[mt], vmax[mt]);
                        sc[mt] = __expf(mreg[mt] - mn);
                        mreg[mt] = mn;
                        lreg[mt] *= sc[mt];
                    }
                    #pragma unroll
                    for (int mt = 0; mt < 2; mt++)
                        #pragma unroll
                        for (int j = 0; j < 4; j++) {
                            float scj = __shfl(sc[mt], 4 * hig + j);   // to o-layout (q = 4*hig+j)
                            #pragma unroll
                            for (int ntd = 0; ntd < 8; ntd++) o[mt][ntd][j] *= scj;
                        }
                }
                // exp + row sum
                #pragma unroll
                for (int mt = 0; mt < 2; mt++) {
                    float rs = 0.f;
                    #pragma unroll
                    for (int nt = 0; nt < 4; nt++)
                        #pragma unroll
                        for (int j = 0; j < 4; j++) {
                            float p = __expf(s[mt][nt][j] - mreg[mt]);
                            s[mt][nt][j] = p;
                            rs += p;
                        }
                    rs += __shfl_xor(rs, 16);
                    rs += __shfl_xor(rs, 32);
                    lreg[mt] += rs;
                }

                // P -> per-wave LDS (one b64 per nt), swizzled
                #pragma unroll
                for (int mt = 0; mt < 2; mt++) {
                    int rr = mt * 16 + ln15;
                    int rx = (rr & 7) << 4;
                    #pragma unroll
                    for (int nt = 0; nt < 4; nt++) {
                        us4 pk = { f2bf(s[mt][nt][0]), f2bf(s[mt][nt][1]),
                                   f2bf(s[mt][nt][2]), f2bf(s[mt][nt][3]) };
                        int addr = rr * 128 + ((nt * 32 + hig * 8) ^ rx);
                        *(us4*)(lPc + addr) = pk;
                    }
                }

                // PV: o += P x V
                #pragma unroll
                for (int ks2 = 0; ks2 < 2; ks2++) {
                    bf16x8 pf[2];
                    #pragma unroll
                    for (int mt = 0; mt < 2; mt++) {
                        int row = mt * 16 + ln15;
                        pf[mt] = *(const bf16x8*)(lPc + row * 128 + (((ks2 * 32 + hi8) * 2) ^ ((row & 7) << 4)));
                    }
                    #pragma unroll
                    for (int ntd = 0; ntd < 8; ntd++) {
                        int drow = ntd * 16 + ln15;
                        bf16x8 vf = *(const bf16x8*)(lVb + drow * 128 + (((ks2 * 32 + hi8) * 2) ^ ((drow & 7) << 4)));
                        __builtin_amdgcn_s_setprio(1);
                        #pragma unroll
                        for (int mt = 0; mt < 2; mt++)
                            o[mt][ntd] = __builtin_amdgcn_mfma_f32_16x16x32_bf16(pf[mt], vf, o[mt][ntd], 0, 0, 0);
                        __builtin_amdgcn_s_setprio(0);
                    }
                }
            }

            __builtin_amdgcn_s_barrier();      // all waves done reading buf before restage
            if (it + 2 < ntiles) stageKV(buf, kv0 + 128);
        }

        // epilogue: o[mt][ntd][j] is q = qw+mt*16+4*hig+j, d = ntd*16+ln15; lreg at q=ln15
        #pragma unroll
        for (int mt = 0; mt < 2; mt++)
            #pragma unroll
            for (int j = 0; j < 4; j++) {
                float inv = 1.0f / __shfl(lreg[mt], 4 * hig + j);
                int t = qw + mt * 16 + hig * 4 + j;
                #pragma unroll
                for (int ntd = 0; ntd < 8; ntd++) {
                    int d = ntd * 16 + ln15;
                    outp[((size_t)b * 2048 + t) * 2048 + h * 128 + d] = f2bf(o[mt][ntd][j] * inv);
                }
            }
    }
}

// ---------- launcher ----------
extern "C" void kernel_launch(void* const* d_in, const int* in_sizes, int n_in,
                              void* d_out, int out_size, void* d_ws, size_t ws_size,
                              hipStream_t stream) {
    const float* x     = (const float*)d_in[0];
    const float* wqkv  = (const float*)d_in[1];
    const float* wo    = (const float*)d_in[2];
    const float* ropeC = (const float*)d_in[3];
    const float* ropeS = (const float*)d_in[4];
    float* out = (float*)d_out;
    char* ws = (char*)d_ws;
    const size_t MB = 1024 * 1024;
    unsigned short* xb    = (unsigned short*)(ws);                  // 32 MB
    unsigned short* wqkvT = (unsigned short*)(ws + 32 * MB);        // 24 MB
    unsigned short* woT   = (unsigned short*)(ws + 56 * MB);        // 8 MB
    unsigned short* qb    = (unsigned short*)(ws + 64 * MB);        // 32 MB
    unsigned short* kb    = (unsigned short*)(ws + 96 * MB);        // 32 MB
    unsigned short* vTb   = (unsigned short*)(ws + 128 * MB);       // 32 MB
    unsigned short* attnb = (unsigned short*)(ws + 160 * MB);       // 32 MB

    cvt_f32_bf16<<<16384, 256, 0, stream>>>(x, xb, 4194304);
    tcvt<<<dim3(192, 64), 256, 0, stream>>>(wqkv, wqkvT, 2048, 6144);
    tcvt<<<dim3(64, 64), 256, 0, stream>>>(wo, woT, 2048, 2048);
    gemm8p<1><<<dim3(24, 32), 512, 0, stream>>>(xb, wqkvT, 8192, 6144, 2048,
                                                nullptr, qb, kb, vTb, ropeC, ropeS, 8, 12);
    attn_fwd<<<dim3(64, 8), 256, 0, stream>>>(qb, kb, vTb, attnb);
    gemm8p<0><<<dim3(8, 32), 512, 0, stream>>>(attnb, woT, 8192, 2048, 2048,
                                               out, nullptr, nullptr, nullptr, nullptr, nullptr, 4, 8);
}

// Round 7
// 421.410 us; speedup vs baseline: 2.0526x; 1.0304x over previous
//
#include <hip/hip_runtime.h>
#include <hip/hip_bf16.h>

// ---------- types ----------
typedef __attribute__((ext_vector_type(8))) __bf16 bf16x8;
typedef __attribute__((ext_vector_type(4))) float f32x4;
typedef __attribute__((ext_vector_type(4))) unsigned short us4;

__device__ __forceinline__ unsigned short f2bf(float f) {
    unsigned u = __float_as_uint(f);
    u += 0x7FFFu + ((u >> 16) & 1u);   // RNE
    return (unsigned short)(u >> 16);
}

__device__ __forceinline__ void gload16(const void* g, void* l) {
    __builtin_amdgcn_global_load_lds(
        (const __attribute__((address_space(1))) unsigned int*)g,
        (__attribute__((address_space(3))) unsigned int*)l,
        16, 0, 0);
}

// ---------- kernel 1: fp32 -> bf16 (x) ----------
__global__ void cvt_f32_bf16(const float* __restrict__ in, unsigned short* __restrict__ out, int n4) {
    int i = blockIdx.x * blockDim.x + threadIdx.x;
    if (i >= n4) return;
    float4 v = ((const float4*)in)[i];
    us4 r = { f2bf(v.x), f2bf(v.y), f2bf(v.z), f2bf(v.w) };
    ((us4*)out)[i] = r;
}

// ---------- kernel 2: transpose + convert: in[R][C] f32 -> out[C][R] bf16 ----------
__global__ void tcvt(const float* __restrict__ in, unsigned short* __restrict__ out, int R, int C) {
    __shared__ float tile[32][33];
    int tx = threadIdx.x & 31, ty = threadIdx.x >> 5;  // 256 threads
    int c0 = blockIdx.x * 32, r0 = blockIdx.y * 32;
    #pragma unroll
    for (int i = 0; i < 32; i += 8)
        tile[ty + i][tx] = in[(size_t)(r0 + ty + i) * C + c0 + tx];
    __syncthreads();
    #pragma unroll
    for (int i = 0; i < 32; i += 8)
        out[(size_t)(c0 + ty + i) * R + r0 + tx] = f2bf(tile[tx][ty + i]);
}

// ---------- 256x256 GEMM (B^T input), BK=64, 2 phases/K-tile, 32 MFMA/phase, 512 thr ----------
#define MF(af, bf, fi, ni) acc[fi][ni] = __builtin_amdgcn_mfma_f32_16x16x32_bf16(af, bf, acc[fi][ni], 0, 0, 0)
#define LOADA(p, off) do { a0 = *(const bf16x8*)((p)+(off)); a1 = *(const bf16x8*)((p)+(off)+1024); \
                           a2 = *(const bf16x8*)((p)+(off)+2048); a3 = *(const bf16x8*)((p)+(off)+3072); } while(0)
#define LOADA2(p, off) do { a4 = *(const bf16x8*)((p)+(off)); a5 = *(const bf16x8*)((p)+(off)+1024); \
                            a6 = *(const bf16x8*)((p)+(off)+2048); a7 = *(const bf16x8*)((p)+(off)+3072); } while(0)
#define LOADB(p) do { b0 = *(const bf16x8*)(p); b1 = *(const bf16x8*)((p)+1024); \
                      b2 = *(const bf16x8*)((p)+2048); b3 = *(const bf16x8*)((p)+3072); } while(0)
#define MFMA32() do { \
    MF(a0,b0,0,0); MF(a0,b1,0,1); MF(a0,b2,0,2); MF(a0,b3,0,3); \
    MF(a1,b0,1,0); MF(a1,b1,1,1); MF(a1,b2,1,2); MF(a1,b3,1,3); \
    MF(a2,b0,2,0); MF(a2,b1,2,1); MF(a2,b2,2,2); MF(a2,b3,2,3); \
    MF(a3,b0,3,0); MF(a3,b1,3,1); MF(a3,b2,3,2); MF(a3,b3,3,3); \
    MF(a4,b0,4,0); MF(a4,b1,4,1); MF(a4,b2,4,2); MF(a4,b3,4,3); \
    MF(a5,b0,5,0); MF(a5,b1,5,1); MF(a5,b2,5,2); MF(a5,b3,5,3); \
    MF(a6,b0,6,0); MF(a6,b1,6,1); MF(a6,b2,6,2); MF(a6,b3,6,3); \
    MF(a7,b0,7,0); MF(a7,b1,7,1); MF(a7,b2,7,2); MF(a7,b3,7,3); } while(0)
#define STG(gb, lp, buf, kkk, kt) do { \
    size_t ko = (size_t)(kt) * 128 + (kkk) * 64; \
    char* lpp = (lp) + (buf) * 32768 + (kkk) * 16384; \
    gload16((gb) + sR0 + ko, lpp + dst0); \
    gload16((gb) + sR1 + ko, lpp + dst1); } while (0)
#define PHASE_SYNC() do { \
    __builtin_amdgcn_s_barrier(); \
    asm volatile("s_waitcnt lgkmcnt(0)" ::: "memory"); \
    __builtin_amdgcn_sched_barrier(0); } while (0)

template <int MODE>
__global__ __launch_bounds__(512) void gemm8p(
    const unsigned short* __restrict__ A, const unsigned short* __restrict__ Bt,
    int M, int N, int K, float* __restrict__ Cf,
    unsigned short* __restrict__ qp, unsigned short* __restrict__ kp,
    unsigned short* __restrict__ vTp,
    const float* __restrict__ ropeC, const float* __restrict__ ropeS,
    int cby, int cbx)
{
    __shared__ unsigned short lA[2][2][8192];   // 64 KB
    __shared__ unsigned short lB[2][2][8192];   // 64 KB
    const int tid = threadIdx.x;
    const int lane = tid & 63, wid = tid >> 6;
    const int ln15 = lane & 15, hig = lane >> 4;
    const int wr = wid >> 2, wc = wid & 3;

    // 2D-chunk XCD swizzle: 8 chunks of (cby x cbx) blocks, chunk = flat & 7
    int nwg = gridDim.x * gridDim.y;
    int flat = blockIdx.y * gridDim.x + blockIdx.x;
    int bx, by;
    if ((nwg & 7) == 0) {
        int c = flat & 7, local = flat >> 3;
        int chunkCols = gridDim.x / cbx;
        by = (c / chunkCols) * cby + local / cbx;
        bx = (c % chunkCols) * cbx + local % cbx;
    } else {
        bx = flat % gridDim.x; by = flat / gridDim.x;
    }
    const int mbase = by * 256, nbase = bx * 256;
    const size_t Kb = (size_t)K * 2;

    const char* Ag = (const char*)A + (size_t)mbase * Kb;
    const char* Bg = (const char*)Bt + (size_t)nbase * Kb;
    char* lAc = (char*)&lA[0][0][0];
    char* lBc = (char*)&lB[0][0][0];

    const int srow = tid >> 2;
    const int gsrc = (tid & 3) ^ (((tid >> 5) & 1) << 1);   // inverse-swizzled k-group
    const size_t sR0 = (size_t)srow * Kb + gsrc * 16;
    const size_t sR1 = (size_t)(srow + 128) * Kb + gsrc * 16;
    const int dst0 = tid * 16, dst1 = (tid + 512) * 16;

    const int colOff = (hig * 16) ^ (((ln15 >> 3) & 1) << 5);
    const int aRow = (wr * 128 + ln15) * 64 + colOff;
    const int bRow = (wc * 64 + ln15) * 64 + colOff;

    f32x4 acc[8][4] = {};
    const int T = K >> 6;

    // prologue: stage t0 fully (k0 pair then k1 pair)
    STG(Ag, lAc, 0, 0, 0);
    STG(Bg, lBc, 0, 0, 0);
    STG(Ag, lAc, 0, 1, 0);
    STG(Bg, lBc, 0, 1, 0);
    asm volatile("s_waitcnt vmcnt(4)" ::: "memory");   // t0-k0 panels landed
    __builtin_amdgcn_s_barrier();

    for (int t = 0; t < T; t++) {
        const int cur = t & 1, nxt = cur ^ 1;
        const char* pa0 = lAc + cur * 32768 + aRow;
        const char* pb0 = lBc + cur * 32768 + bRow;
        const char* pa1 = pa0 + 16384;
        const char* pb1 = pb0 + 16384;
        const bool more = (t + 1 < T);
        bf16x8 a0, a1, a2, a3, a4, a5, a6, a7, b0, b1, b2, b3;

        // ---- ph1: kk0, all 8 m-frags (32 MFMA) ----
        LOADA(pa0, 0);
        LOADA2(pa0, 4096);
        LOADB(pb0);
        if (more) { STG(Ag, lAc, nxt, 0, t + 1); STG(Bg, lBc, nxt, 0, t + 1); }
        asm volatile("s_waitcnt lgkmcnt(8)" ::: "memory");   // let early ds_reads drain
        if (more) asm volatile("s_waitcnt vmcnt(4)" ::: "memory");   // retire t-k1 pair
        else      asm volatile("s_waitcnt vmcnt(0)" ::: "memory");
        PHASE_SYNC();
        __builtin_amdgcn_s_setprio(1);
        MFMA32();
        __builtin_amdgcn_s_setprio(0);
        __builtin_amdgcn_s_barrier();

        // ---- ph2: kk1, all 8 m-frags (32 MFMA) ----
        LOADA(pa1, 0);
        LOADA2(pa1, 4096);
        LOADB(pb1);
        if (more) {
            STG(Ag, lAc, nxt, 1, t + 1);
            STG(Bg, lBc, nxt, 1, t + 1);
            asm volatile("s_waitcnt lgkmcnt(8)" ::: "memory");
            asm volatile("s_waitcnt vmcnt(4)" ::: "memory");   // retire (t+1)-k0 pair
        }
        PHASE_SYNC();
        __builtin_amdgcn_s_setprio(1);
        MFMA32();
        __builtin_amdgcn_s_setprio(0);
        __builtin_amdgcn_s_barrier();
    }

    if (MODE == 0) {
        #pragma unroll
        for (int fg = 0; fg < 8; fg++)
            #pragma unroll
            for (int n = 0; n < 4; n++)
                #pragma unroll
                for (int j = 0; j < 4; j++) {
                    int m = mbase + wr * 128 + fg * 16 + hig * 4 + j;
                    int col = nbase + wc * 64 + n * 16 + ln15;
                    Cf[(size_t)m * N + col] = acc[fg][n][j];
                }
    } else {
        const int colb = nbase + wc * 64;
        const int sec = colb >> 11;               // 0=q, 1=k, 2=v
        if (sec < 2) {
            unsigned short* dst = (sec == 0) ? qp : kp;
            const float scale = (sec == 0) ? 0.08838834764831845f : 1.0f;
            #pragma unroll
            for (int fg = 0; fg < 8; fg++)
                #pragma unroll
                for (int n = 0; n < 4; n++) {
                    int within = (colb & 2047) + n * 16 + ln15;
                    int h = within >> 7, d = within & 127, pidx = d >> 1;
                    #pragma unroll
                    for (int j = 0; j < 4; j++) {
                        int m = mbase + wr * 128 + fg * 16 + hig * 4 + j;
                        int b = m >> 11, tq = m & 2047;
                        float v = acc[fg][n][j];
                        float pv = __shfl_xor(v, 1);
                        float c = ropeC[tq * 64 + pidx], s = ropeS[tq * 64 + pidx];
                        float o = (d & 1) ? fmaf(pv, s, v * c) : fmaf(-pv, s, v * c);
                        o *= scale;
                        dst[((size_t)((b << 4) + h) * 2048 + tq) * 128 + d] = f2bf(o);
                    }
                }
        } else {
            #pragma unroll
            for (int fg = 0; fg < 8; fg++)
                #pragma unroll
                for (int n = 0; n < 4; n++) {
                    int within = (colb & 2047) + n * 16 + ln15;
                    int h = within >> 7, d = within & 127;
                    int m0 = mbase + wr * 128 + fg * 16 + hig * 4;
                    int b = m0 >> 11, t0 = m0 & 2047;
                    us4 pk = { f2bf(acc[fg][n][0]), f2bf(acc[fg][n][1]),
                               f2bf(acc[fg][n][2]), f2bf(acc[fg][n][3]) };
                    *(us4*)(vTp + ((size_t)((b << 4) + h) * 128 + d) * 2048 + t0) = pk;
                }
        }
    }
}

// ---------- flash attention, causal, swapped QK^T, K/V double-buffer, counted vmcnt ----------
// grid: (64, 8)  x = bh (XCD locality), y = q-pair.  q,k: [BH][T][D] (q pre-scaled); vT: [BH][D][T]
__global__ __launch_bounds__(256, 2) void attn_fwd(
    const unsigned short* __restrict__ q, const unsigned short* __restrict__ k,
    const unsigned short* __restrict__ vT, unsigned short* __restrict__ outp)
{
    __shared__ unsigned short lK[2][64 * 128];   // 2 x 16 KB, [kv][d], XOR-swizzled rows (256B)
    __shared__ unsigned short lV[2][128 * 64];   // 2 x 16 KB, [d][kv], XOR-swizzled rows (128B)
    __shared__ unsigned short lP[4 * 32 * 64];   // 16 KB, per-wave
    const int tid = threadIdx.x;
    const int lane = tid & 63, wid = tid >> 6;
    const int ln15 = lane & 15, hig = lane >> 4, hi8 = hig * 8;
    const int bh = blockIdx.x;

    const char* qg = (const char*)(q + (size_t)bh * 2048 * 128);
    const char* kg = (const char*)(k + (size_t)bh * 2048 * 128);
    const char* vg = (const char*)(vT + (size_t)bh * 128 * 2048);
    char* lKc = (char*)&lK[0][0];
    char* lVc = (char*)&lV[0][0];
    char* lPc = (char*)lP + wid * (32 * 64 * 2);
    const int b = bh >> 4, h = bh & 15;

    for (int rep = 0; rep < 2; rep++) {
        const int qt = rep == 0 ? (int)blockIdx.y : 15 - (int)blockIdx.y;
        const int qbase = qt * 128;
        const int qw = qbase + wid * 32;

        bf16x8 qf[2][4];
        #pragma unroll
        for (int mt = 0; mt < 2; mt++)
            #pragma unroll
            for (int ks = 0; ks < 4; ks++)
                qf[mt][ks] = *(const bf16x8*)(qg + ((size_t)(qw + mt * 16 + ln15) * 128 + ks * 32 + hi8) * 2);

        f32x4 o[2][8] = {};
        float mreg[2] = { -1e30f, -1e30f };
        float lreg[2] = { 0.f, 0.f };

        auto stageKV = [&](int bf, int kv0) {
            #pragma unroll
            for (int i = 0; i < 4; i++) {
                int slot = tid + i * 256;
                int row = slot >> 4, c = (slot & 15) * 16;
                gload16(kg + (size_t)(kv0 + row) * 256 + (c ^ ((row & 7) << 4)),
                        lKc + bf * 16384 + slot * 16);
            }
            #pragma unroll
            for (int i = 0; i < 4; i++) {
                int slot = tid + i * 256;
                int d = slot >> 3, c = (slot & 7) * 16;
                gload16(vg + (size_t)d * 4096 + (size_t)kv0 * 2 + (c ^ ((d & 7) << 4)),
                        lVc + bf * 16384 + slot * 16);
            }
        };

        const int ntiles = (qbase >> 6) + 2;   // >= 2 always
        stageKV(0, 0);
        if (ntiles > 1) stageKV(1, 64);

        for (int it = 0; it < ntiles; it++) {
            const int kv0 = it * 64;
            const int buf = it & 1;
            if (it + 1 < ntiles) asm volatile("s_waitcnt vmcnt(8)" ::: "memory");
            else                 asm volatile("s_waitcnt vmcnt(0)" ::: "memory");
            __builtin_amdgcn_s_barrier();

            if (kv0 <= qw + 31) {   // wave-active (causal range)
                const char* lKb = lKc + buf * 16384;
                const char* lVb = lVc + buf * 16384;

                f32x4 s[2][4] = {};
                #pragma unroll
                for (int ks = 0; ks < 4; ks++) {
                    bf16x8 kf[4];
                    #pragma unroll
                    for (int nt = 0; nt < 4; nt++) {
                        int row = nt * 16 + ln15;
                        kf[nt] = *(const bf16x8*)(lKb + row * 256 + (((ks * 32 + hi8) * 2) ^ ((row & 7) << 4)));
                    }
                    __builtin_amdgcn_s_setprio(1);
                    #pragma unroll
                    for (int mt = 0; mt < 2; mt++)
                        #pragma unroll
                        for (int nt = 0; nt < 4; nt++)
                            s[mt][nt] = __builtin_amdgcn_mfma_f32_16x16x32_bf16(kf[nt], qf[mt][ks], s[mt][nt], 0, 0, 0);
                    __builtin_amdgcn_s_setprio(0);
                }

                if (kv0 + 63 > qw) {  // diagonal tile: mask kv > q
                    #pragma unroll
                    for (int mt = 0; mt < 2; mt++) {
                        int qi = qw + mt * 16 + ln15;
                        #pragma unroll
                        for (int nt = 0; nt < 4; nt++)
                            #pragma unroll
                            for (int j = 0; j < 4; j++) {
                                int kvi = kv0 + nt * 16 + 4 * hig + j;
                                if (kvi > qi) s[mt][nt][j] = -1e30f;
                            }
                    }
                }

                float vmax[2];
                #pragma unroll
                for (int mt = 0; mt < 2; mt++) {
                    float v = fmaxf(fmaxf(s[mt][0][0], s[mt][0][1]), fmaxf(s[mt][0][2], s[mt][0][3]));
                    #pragma unroll
                    for (int nt = 1; nt < 4; nt++)
                        v = fmaxf(v, fmaxf(fmaxf(s[mt][nt][0], s[mt][nt][1]), fmaxf(s[mt][nt][2], s[mt][nt][3])));
                    v = fmaxf(v, __shfl_xor(v, 16));
                    v = fmaxf(v, __shfl_xor(v, 32));
                    vmax[mt] = v;
                }
                bool grow = (vmax[0] > mreg[0] + 8.0f) || (vmax[1] > mreg[1] + 8.0f);
                if (__any(grow)) {
                    float sc[2];
                    #pragma unroll
                    for (int mt = 0; mt < 2; mt++) {
                        float mn = fmaxf(mreg[mt], vmax[mt]);
                        sc[mt] = __expf(mreg[mt] - mn);
                        mreg[mt] = mn;
                        lreg[mt] *= sc[mt];
                    }
                    #pragma unroll
                    for (int mt = 0; mt < 2; mt++)
                        #pragma unroll
                        for (int j = 0; j < 4; j++) {
                            float scj = __shfl(sc[mt], 4 * hig + j);
                            #pragma unroll
                            for (int ntd = 0; ntd < 8; ntd++) o[mt][ntd][j] *= scj;
                        }
                }
                #pragma unroll
                for (int mt = 0; mt < 2; mt++) {
                    float rs = 0.f;
                    #pragma unroll
                    for (int nt = 0; nt < 4; nt++)
                        #pragma unroll
                        for (int j = 0; j < 4; j++) {
                            float p = __expf(s[mt][nt][j] - mreg[mt]);
                            s[mt][nt][j] = p;
                            rs += p;
                        }
                    rs += __shfl_xor(rs, 16);
                    rs += __shfl_xor(rs, 32);
                    lreg[mt] += rs;
                }

                #pragma unroll
                for (int mt = 0; mt < 2; mt++) {
                    int rr = mt * 16 + ln15;
                    int rx = (rr & 7) << 4;
                    #pragma unroll
                    for (int nt = 0; nt < 4; nt++) {
                        us4 pk = { f2bf(s[mt][nt][0]), f2bf(s[mt][nt][1]),
                                   f2bf(s[mt][nt][2]), f2bf(s[mt][nt][3]) };
                        int addr = rr * 128 + ((nt * 32 + hig * 8) ^ rx);
                        *(us4*)(lPc + addr) = pk;
                    }
                }

                #pragma unroll
                for (int ks2 = 0; ks2 < 2; ks2++) {
                    bf16x8 pf[2];
                    #pragma unroll
                    for (int mt = 0; mt < 2; mt++) {
                        int row = mt * 16 + ln15;
                        pf[mt] = *(const bf16x8*)(lPc + row * 128 + (((ks2 * 32 + hi8) * 2) ^ ((row & 7) << 4)));
                    }
                    #pragma unroll
                    for (int ntd = 0; ntd < 8; ntd++) {
                        int drow = ntd * 16 + ln15;
                        bf16x8 vf = *(const bf16x8*)(lVb + drow * 128 + (((ks2 * 32 + hi8) * 2) ^ ((drow & 7) << 4)));
                        __builtin_amdgcn_s_setprio(1);
                        #pragma unroll
                        for (int mt = 0; mt < 2; mt++)
                            o[mt][ntd] = __builtin_amdgcn_mfma_f32_16x16x32_bf16(pf[mt], vf, o[mt][ntd], 0, 0, 0);
                        __builtin_amdgcn_s_setprio(0);
                    }
                }
            }

            __builtin_amdgcn_s_barrier();
            if (it + 2 < ntiles) stageKV(buf, kv0 + 128);
        }

        #pragma unroll
        for (int mt = 0; mt < 2; mt++)
            #pragma unroll
            for (int j = 0; j < 4; j++) {
                float inv = 1.0f / __shfl(lreg[mt], 4 * hig + j);
                int t = qw + mt * 16 + hig * 4 + j;
                #pragma unroll
                for (int ntd = 0; ntd < 8; ntd++) {
                    int d = ntd * 16 + ln15;
                    outp[((size_t)b * 2048 + t) * 2048 + h * 128 + d] = f2bf(o[mt][ntd][j] * inv);
                }
            }
    }
}

// ---------- launcher ----------
extern "C" void kernel_launch(void* const* d_in, const int* in_sizes, int n_in,
                              void* d_out, int out_size, void* d_ws, size_t ws_size,
                              hipStream_t stream) {
    const float* x     = (const float*)d_in[0];
    const float* wqkv  = (const float*)d_in[1];
    const float* wo    = (const float*)d_in[2];
    const float* ropeC = (const float*)d_in[3];
    const float* ropeS = (const float*)d_in[4];
    float* out = (float*)d_out;
    char* ws = (char*)d_ws;
    const size_t MB = 1024 * 1024;
    unsigned short* xb    = (unsigned short*)(ws);                  // 32 MB
    unsigned short* wqkvT = (unsigned short*)(ws + 32 * MB);        // 24 MB
    unsigned short* woT   = (unsigned short*)(ws + 56 * MB);        // 8 MB
    unsigned short* qb    = (unsigned short*)(ws + 64 * MB);        // 32 MB
    unsigned short* kb    = (unsigned short*)(ws + 96 * MB);        // 32 MB
    unsigned short* vTb   = (unsigned short*)(ws + 128 * MB);       // 32 MB
    unsigned short* attnb = (unsigned short*)(ws + 160 * MB);       // 32 MB

    cvt_f32_bf16<<<16384, 256, 0, stream>>>(x, xb, 4194304);
    tcvt<<<dim3(192, 64), 256, 0, stream>>>(wqkv, wqkvT, 2048, 6144);
    tcvt<<<dim3(64, 64), 256, 0, stream>>>(wo, woT, 2048, 2048);
    gemm8p<1><<<dim3(24, 32), 512, 0, stream>>>(xb, wqkvT, 8192, 6144, 2048,
                                                nullptr, qb, kb, vTb, ropeC, ropeS, 8, 12);
    attn_fwd<<<dim3(64, 8), 256, 0, stream>>>(qb, kb, vTb, attnb);
    gemm8p<0><<<dim3(8, 32), 512, 0, stream>>>(attnb, woT, 8192, 2048, 2048,
                                               out, nullptr, nullptr, nullptr, nullptr, nullptr, 4, 8);
}

// Round 8
// 400.664 us; speedup vs baseline: 2.1589x; 1.0518x over previous
//
#include <hip/hip_runtime.h>
#include <hip/hip_bf16.h>

// ---------- types ----------
typedef __attribute__((ext_vector_type(8))) __bf16 bf16x8;
typedef __attribute__((ext_vector_type(4))) float f32x4;
typedef __attribute__((ext_vector_type(4))) unsigned short us4;

__device__ __forceinline__ unsigned short f2bf(float f) {
    unsigned u = __float_as_uint(f);
    u += 0x7FFFu + ((u >> 16) & 1u);   // RNE
    return (unsigned short)(u >> 16);
}

__device__ __forceinline__ void gload16(const void* g, void* l) {
    __builtin_amdgcn_global_load_lds(
        (const __attribute__((address_space(1))) unsigned int*)g,
        (__attribute__((address_space(3))) unsigned int*)l,
        16, 0, 0);
}

// ---------- kernel 1: fp32 -> bf16 (x) ----------
__global__ void cvt_f32_bf16(const float* __restrict__ in, unsigned short* __restrict__ out, int n4) {
    int i = blockIdx.x * blockDim.x + threadIdx.x;
    if (i >= n4) return;
    float4 v = ((const float4*)in)[i];
    us4 r = { f2bf(v.x), f2bf(v.y), f2bf(v.z), f2bf(v.w) };
    ((us4*)out)[i] = r;
}

// ---------- kernel 2: transpose + convert: in[R][C] f32 -> out[C][R] bf16 ----------
__global__ void tcvt(const float* __restrict__ in, unsigned short* __restrict__ out, int R, int C) {
    __shared__ float tile[32][33];
    int tx = threadIdx.x & 31, ty = threadIdx.x >> 5;  // 256 threads
    int c0 = blockIdx.x * 32, r0 = blockIdx.y * 32;
    #pragma unroll
    for (int i = 0; i < 32; i += 8)
        tile[ty + i][tx] = in[(size_t)(r0 + ty + i) * C + c0 + tx];
    __syncthreads();
    #pragma unroll
    for (int i = 0; i < 32; i += 8)
        out[(size_t)(c0 + ty + i) * R + r0 + tx] = f2bf(tile[tx][ty + i]);
}

// ---------- 256x256 GEMM, 16 waves (1024 thr), per-wave 64x64, BK=64, dbuf ----------
// LDS per buf (64 KB): A = 256 rows x 128B at [0,32K), B at [32K,64K). Buf stride 64K.
// Row layout: 8 x 16B slots; slot h of row r holds k-group h ^ (r&7)  (2-way read conflicts = free).
// TLP design: 4 waves/SIMD (VGPR<=128), no intra-tile barriers; compiler pipelines kk0/kk1.
#define MFW(af, bf, fi, ni) acc[fi][ni] = __builtin_amdgcn_mfma_f32_16x16x32_bf16(af, bf, acc[fi][ni], 0, 0, 0)
#define MFMA16W() do { \
    MFW(a0,b0,0,0); MFW(a0,b1,0,1); MFW(a0,b2,0,2); MFW(a0,b3,0,3); \
    MFW(a1,b0,1,0); MFW(a1,b1,1,1); MFW(a1,b2,1,2); MFW(a1,b3,1,3); \
    MFW(a2,b0,2,0); MFW(a2,b1,2,1); MFW(a2,b2,2,2); MFW(a2,b3,2,3); \
    MFW(a3,b0,3,0); MFW(a3,b1,3,1); MFW(a3,b2,3,2); MFW(a3,b3,3,3); } while(0)
#define STGW(kt, bufo) do { \
    size_t ko = (size_t)(kt) * 128; \
    char* bb = L + (bufo); \
    gload16(Ag + sR + ko, bb + dstA); \
    gload16(Ag + sR2 + ko, bb + dstA + 16384); \
    gload16(Bg + sR + ko, bb + 32768 + dstA); \
    gload16(Bg + sR2 + ko, bb + 32768 + dstA + 16384); } while (0)

template <int MODE>
__global__ __launch_bounds__(1024, 4) void gemmw(
    const unsigned short* __restrict__ A, const unsigned short* __restrict__ Bt,
    int M, int N, int K, float* __restrict__ Cf,
    unsigned short* __restrict__ qp, unsigned short* __restrict__ kp,
    unsigned short* __restrict__ vTp,
    const float* __restrict__ ropeC, const float* __restrict__ ropeS,
    int cby, int cbx)
{
    __shared__ unsigned short lds[2][32768];   // 128 KB
    const int tid = threadIdx.x;
    const int lane = tid & 63, wid = tid >> 6;      // wid 0..15
    const int ln15 = lane & 15, hig = lane >> 4;
    const int wrow = wid >> 2, wcol = wid & 3;      // 4x4 wave grid, 64x64 each

    // 2D-chunk XCD swizzle: 8 chunks of (cby x cbx) blocks
    int nwg = gridDim.x * gridDim.y;
    int flat = blockIdx.y * gridDim.x + blockIdx.x;
    int bx, by;
    if ((nwg & 7) == 0) {
        int c = flat & 7, local = flat >> 3;
        int chunkCols = gridDim.x / cbx;
        by = (c / chunkCols) * cby + local / cbx;
        bx = (c % chunkCols) * cbx + local % cbx;
    } else {
        bx = flat % gridDim.x; by = flat / gridDim.x;
    }
    const int mbase = by * 256, nbase = bx * 256;
    const size_t Kb = (size_t)K * 2;

    const char* Ag = (const char*)A + (size_t)mbase * Kb;
    const char* Bg = (const char*)Bt + (size_t)nbase * Kb;
    char* L = (char*)&lds[0][0];

    // staging: thread covers rows (tid>>3) and (tid>>3)+128, slot tid&7 (inverse-swizzled src)
    const int srow = tid >> 3;
    const int gs = (tid & 7) ^ (srow & 7);
    const size_t sR = (size_t)srow * Kb + gs * 16;
    const size_t sR2 = sR + (size_t)128 * Kb;
    const int dstA = tid * 16;

    // fragment read offsets: row = w*64 + f*16 + ln15; slot(kk) = (kk*4+hig) ^ (ln15&7)
    const int aBase = (wrow * 64 + ln15) * 128;
    const int bBase = 32768 + (wcol * 64 + ln15) * 128;
    const int sl0 = (hig ^ (ln15 & 7)) * 16;
    const int sl1 = ((4 + hig) ^ (ln15 & 7)) * 16;

    f32x4 acc[4][4] = {};
    const int T = K >> 6;

    STGW(0, 0);
    asm volatile("s_waitcnt vmcnt(0)" ::: "memory");
    __builtin_amdgcn_s_barrier();
    asm volatile("" ::: "memory");

    for (int t = 0; t < T; t++) {
        char* bb = L + (t & 1) * 65536;
        if (t + 1 < T) STGW(t + 1, ((t + 1) & 1) * 65536);
        bf16x8 a0, a1, a2, a3, b0, b1, b2, b3;
        // kk0
        a0 = *(const bf16x8*)(bb + aBase + 0 * 2048 + sl0);
        a1 = *(const bf16x8*)(bb + aBase + 1 * 2048 + sl0);
        a2 = *(const bf16x8*)(bb + aBase + 2 * 2048 + sl0);
        a3 = *(const bf16x8*)(bb + aBase + 3 * 2048 + sl0);
        b0 = *(const bf16x8*)(bb + bBase + 0 * 2048 + sl0);
        b1 = *(const bf16x8*)(bb + bBase + 1 * 2048 + sl0);
        b2 = *(const bf16x8*)(bb + bBase + 2 * 2048 + sl0);
        b3 = *(const bf16x8*)(bb + bBase + 3 * 2048 + sl0);
        __builtin_amdgcn_s_setprio(1);
        MFMA16W();
        __builtin_amdgcn_s_setprio(0);
        // kk1
        a0 = *(const bf16x8*)(bb + aBase + 0 * 2048 + sl1);
        a1 = *(const bf16x8*)(bb + aBase + 1 * 2048 + sl1);
        a2 = *(const bf16x8*)(bb + aBase + 2 * 2048 + sl1);
        a3 = *(const bf16x8*)(bb + aBase + 3 * 2048 + sl1);
        b0 = *(const bf16x8*)(bb + bBase + 0 * 2048 + sl1);
        b1 = *(const bf16x8*)(bb + bBase + 1 * 2048 + sl1);
        b2 = *(const bf16x8*)(bb + bBase + 2 * 2048 + sl1);
        b3 = *(const bf16x8*)(bb + bBase + 3 * 2048 + sl1);
        __builtin_amdgcn_s_setprio(1);
        MFMA16W();
        __builtin_amdgcn_s_setprio(0);

        if (t + 1 < T) {
            asm volatile("s_waitcnt vmcnt(0)" ::: "memory");   // next tile fully landed
            __builtin_amdgcn_s_barrier();                      // all waves done with bb
            asm volatile("" ::: "memory");
        }
    }

    if (MODE == 0) {
        #pragma unroll
        for (int fm = 0; fm < 4; fm++)
            #pragma unroll
            for (int fn = 0; fn < 4; fn++)
                #pragma unroll
                for (int j = 0; j < 4; j++) {
                    int m = mbase + wrow * 64 + fm * 16 + hig * 4 + j;
                    int col = nbase + wcol * 64 + fn * 16 + ln15;
                    Cf[(size_t)m * N + col] = acc[fm][fn][j];
                }
    } else {
        const int colb = nbase + wcol * 64;
        const int sec = colb >> 11;               // 0=q, 1=k, 2=v
        if (sec < 2) {
            unsigned short* dst = (sec == 0) ? qp : kp;
            const float scale = (sec == 0) ? 0.08838834764831845f : 1.0f;
            #pragma unroll
            for (int fm = 0; fm < 4; fm++)
                #pragma unroll
                for (int fn = 0; fn < 4; fn++) {
                    int within = (colb & 2047) + fn * 16 + ln15;
                    int h = within >> 7, d = within & 127, pidx = d >> 1;
                    #pragma unroll
                    for (int j = 0; j < 4; j++) {
                        int m = mbase + wrow * 64 + fm * 16 + hig * 4 + j;
                        int b = m >> 11, tq = m & 2047;
                        float v = acc[fm][fn][j];
                        float pv = __shfl_xor(v, 1);
                        float c = ropeC[tq * 64 + pidx], s = ropeS[tq * 64 + pidx];
                        float o = (d & 1) ? fmaf(pv, s, v * c) : fmaf(-pv, s, v * c);
                        o *= scale;
                        dst[((size_t)((b << 4) + h) * 2048 + tq) * 128 + d] = f2bf(o);
                    }
                }
        } else {
            #pragma unroll
            for (int fm = 0; fm < 4; fm++)
                #pragma unroll
                for (int fn = 0; fn < 4; fn++) {
                    int within = (colb & 2047) + fn * 16 + ln15;
                    int h = within >> 7, d = within & 127;
                    int m0 = mbase + wrow * 64 + fm * 16 + hig * 4;
                    int b = m0 >> 11, t0 = m0 & 2047;
                    us4 pk = { f2bf(acc[fm][fn][0]), f2bf(acc[fm][fn][1]),
                               f2bf(acc[fm][fn][2]), f2bf(acc[fm][fn][3]) };
                    *(us4*)(vTp + ((size_t)((b << 4) + h) * 128 + d) * 2048 + t0) = pk;
                }
        }
    }
}

// ---------- flash attention, causal, swapped QK^T, K/V double-buffer, counted vmcnt ----------
// grid: (64, 8)  x = bh (XCD locality), y = q-pair.  q,k: [BH][T][D] (q pre-scaled); vT: [BH][D][T]
__global__ __launch_bounds__(256, 2) void attn_fwd(
    const unsigned short* __restrict__ q, const unsigned short* __restrict__ k,
    const unsigned short* __restrict__ vT, unsigned short* __restrict__ outp)
{
    __shared__ unsigned short lK[2][64 * 128];   // 2 x 16 KB, [kv][d], XOR-swizzled rows (256B)
    __shared__ unsigned short lV[2][128 * 64];   // 2 x 16 KB, [d][kv], XOR-swizzled rows (128B)
    __shared__ unsigned short lP[4 * 32 * 64];   // 16 KB, per-wave
    const int tid = threadIdx.x;
    const int lane = tid & 63, wid = tid >> 6;
    const int ln15 = lane & 15, hig = lane >> 4, hi8 = hig * 8;
    const int bh = blockIdx.x;

    const char* qg = (const char*)(q + (size_t)bh * 2048 * 128);
    const char* kg = (const char*)(k + (size_t)bh * 2048 * 128);
    const char* vg = (const char*)(vT + (size_t)bh * 128 * 2048);
    char* lKc = (char*)&lK[0][0];
    char* lVc = (char*)&lV[0][0];
    char* lPc = (char*)lP + wid * (32 * 64 * 2);
    const int b = bh >> 4, h = bh & 15;

    for (int rep = 0; rep < 2; rep++) {
        const int qt = rep == 0 ? (int)blockIdx.y : 15 - (int)blockIdx.y;
        const int qbase = qt * 128;
        const int qw = qbase + wid * 32;

        bf16x8 qf[2][4];
        #pragma unroll
        for (int mt = 0; mt < 2; mt++)
            #pragma unroll
            for (int ks = 0; ks < 4; ks++)
                qf[mt][ks] = *(const bf16x8*)(qg + ((size_t)(qw + mt * 16 + ln15) * 128 + ks * 32 + hi8) * 2);

        f32x4 o[2][8] = {};
        float mreg[2] = { -1e30f, -1e30f };
        float lreg[2] = { 0.f, 0.f };

        auto stageKV = [&](int bf, int kv0) {
            #pragma unroll
            for (int i = 0; i < 4; i++) {
                int slot = tid + i * 256;
                int row = slot >> 4, c = (slot & 15) * 16;
                gload16(kg + (size_t)(kv0 + row) * 256 + (c ^ ((row & 7) << 4)),
                        lKc + bf * 16384 + slot * 16);
            }
            #pragma unroll
            for (int i = 0; i < 4; i++) {
                int slot = tid + i * 256;
                int d = slot >> 3, c = (slot & 7) * 16;
                gload16(vg + (size_t)d * 4096 + (size_t)kv0 * 2 + (c ^ ((d & 7) << 4)),
                        lVc + bf * 16384 + slot * 16);
            }
        };

        const int ntiles = (qbase >> 6) + 2;   // >= 2 always
        stageKV(0, 0);
        if (ntiles > 1) stageKV(1, 64);

        for (int it = 0; it < ntiles; it++) {
            const int kv0 = it * 64;
            const int buf = it & 1;
            if (it + 1 < ntiles) asm volatile("s_waitcnt vmcnt(8)" ::: "memory");
            else                 asm volatile("s_waitcnt vmcnt(0)" ::: "memory");
            __builtin_amdgcn_s_barrier();

            if (kv0 <= qw + 31) {   // wave-active (causal range)
                const char* lKb = lKc + buf * 16384;
                const char* lVb = lVc + buf * 16384;

                f32x4 s[2][4] = {};
                #pragma unroll
                for (int ks = 0; ks < 4; ks++) {
                    bf16x8 kf[4];
                    #pragma unroll
                    for (int nt = 0; nt < 4; nt++) {
                        int row = nt * 16 + ln15;
                        kf[nt] = *(const bf16x8*)(lKb + row * 256 + (((ks * 32 + hi8) * 2) ^ ((row & 7) << 4)));
                    }
                    __builtin_amdgcn_s_setprio(1);
                    #pragma unroll
                    for (int mt = 0; mt < 2; mt++)
                        #pragma unroll
                        for (int nt = 0; nt < 4; nt++)
                            s[mt][nt] = __builtin_amdgcn_mfma_f32_16x16x32_bf16(kf[nt], qf[mt][ks], s[mt][nt], 0, 0, 0);
                    __builtin_amdgcn_s_setprio(0);
                }

                if (kv0 + 63 > qw) {  // diagonal tile: mask kv > q
                    #pragma unroll
                    for (int mt = 0; mt < 2; mt++) {
                        int qi = qw + mt * 16 + ln15;
                        #pragma unroll
                        for (int nt = 0; nt < 4; nt++)
                            #pragma unroll
                            for (int j = 0; j < 4; j++) {
                                int kvi = kv0 + nt * 16 + 4 * hig + j;
                                if (kvi > qi) s[mt][nt][j] = -1e30f;
                            }
                    }
                }

                float vmax[2];
                #pragma unroll
                for (int mt = 0; mt < 2; mt++) {
                    float v = fmaxf(fmaxf(s[mt][0][0], s[mt][0][1]), fmaxf(s[mt][0][2], s[mt][0][3]));
                    #pragma unroll
                    for (int nt = 1; nt < 4; nt++)
                        v = fmaxf(v, fmaxf(fmaxf(s[mt][nt][0], s[mt][nt][1]), fmaxf(s[mt][nt][2], s[mt][nt][3])));
                    v = fmaxf(v, __shfl_xor(v, 16));
                    v = fmaxf(v, __shfl_xor(v, 32));
                    vmax[mt] = v;
                }
                bool grow = (vmax[0] > mreg[0] + 8.0f) || (vmax[1] > mreg[1] + 8.0f);
                if (__any(grow)) {
                    float sc[2];
                    #pragma unroll
                    for (int mt = 0; mt < 2; mt++) {
                        float mn = fmaxf(mreg[mt], vmax[mt]);
                        sc[mt] = __expf(mreg[mt] - mn);
                        mreg[mt] = mn;
                        lreg[mt] *= sc[mt];
                    }
                    #pragma unroll
                    for (int mt = 0; mt < 2; mt++)
                        #pragma unroll
                        for (int j = 0; j < 4; j++) {
                            float scj = __shfl(sc[mt], 4 * hig + j);
                            #pragma unroll
                            for (int ntd = 0; ntd < 8; ntd++) o[mt][ntd][j] *= scj;
                        }
                }
                #pragma unroll
                for (int mt = 0; mt < 2; mt++) {
                    float rs = 0.f;
                    #pragma unroll
                    for (int nt = 0; nt < 4; nt++)
                        #pragma unroll
                        for (int j = 0; j < 4; j++) {
                            float p = __expf(s[mt][nt][j] - mreg[mt]);
                            s[mt][nt][j] = p;
                            rs += p;
                        }
                    rs += __shfl_xor(rs, 16);
                    rs += __shfl_xor(rs, 32);
                    lreg[mt] += rs;
                }

                #pragma unroll
                for (int mt = 0; mt < 2; mt++) {
                    int rr = mt * 16 + ln15;
                    int rx = (rr & 7) << 4;
                    #pragma unroll
                    for (int nt = 0; nt < 4; nt++) {
                        us4 pk = { f2bf(s[mt][nt][0]), f2bf(s[mt][nt][1]),
                                   f2bf(s[mt][nt][2]), f2bf(s[mt][nt][3]) };
                        int addr = rr * 128 + ((nt * 32 + hig * 8) ^ rx);
                        *(us4*)(lPc + addr) = pk;
                    }
                }

                #pragma unroll
                for (int ks2 = 0; ks2 < 2; ks2++) {
                    bf16x8 pf[2];
                    #pragma unroll
                    for (int mt = 0; mt < 2; mt++) {
                        int row = mt * 16 + ln15;
                        pf[mt] = *(const bf16x8*)(lPc + row * 128 + (((ks2 * 32 + hi8) * 2) ^ ((row & 7) << 4)));
                    }
                    #pragma unroll
                    for (int ntd = 0; ntd < 8; ntd++) {
                        int drow = ntd * 16 + ln15;
                        bf16x8 vf = *(const bf16x8*)(lVb + drow * 128 + (((ks2 * 32 + hi8) * 2) ^ ((drow & 7) << 4)));
                        __builtin_amdgcn_s_setprio(1);
                        #pragma unroll
                        for (int mt = 0; mt < 2; mt++)
                            o[mt][ntd] = __builtin_amdgcn_mfma_f32_16x16x32_bf16(pf[mt], vf, o[mt][ntd], 0, 0, 0);
                        __builtin_amdgcn_s_setprio(0);
                    }
                }
            }

            __builtin_amdgcn_s_barrier();
            if (it + 2 < ntiles) stageKV(buf, kv0 + 128);
        }

        #pragma unroll
        for (int mt = 0; mt < 2; mt++)
            #pragma unroll
            for (int j = 0; j < 4; j++) {
                float inv = 1.0f / __shfl(lreg[mt], 4 * hig + j);
                int t = qw + mt * 16 + hig * 4 + j;
                #pragma unroll
                for (int ntd = 0; ntd < 8; ntd++) {
                    int d = ntd * 16 + ln15;
                    outp[((size_t)b * 2048 + t) * 2048 + h * 128 + d] = f2bf(o[mt][ntd][j] * inv);
                }
            }
    }
}

// ---------- launcher ----------
extern "C" void kernel_launch(void* const* d_in, const int* in_sizes, int n_in,
                              void* d_out, int out_size, void* d_ws, size_t ws_size,
                              hipStream_t stream) {
    const float* x     = (const float*)d_in[0];
    const float* wqkv  = (const float*)d_in[1];
    const float* wo    = (const float*)d_in[2];
    const float* ropeC = (const float*)d_in[3];
    const float* ropeS = (const float*)d_in[4];
    float* out = (float*)d_out;
    char* ws = (char*)d_ws;
    const size_t MB = 1024 * 1024;
    unsigned short* xb    = (unsigned short*)(ws);                  // 32 MB
    unsigned short* wqkvT = (unsigned short*)(ws + 32 * MB);        // 24 MB
    unsigned short* woT   = (unsigned short*)(ws + 56 * MB);        // 8 MB
    unsigned short* qb    = (unsigned short*)(ws + 64 * MB);        // 32 MB
    unsigned short* kb    = (unsigned short*)(ws + 96 * MB);        // 32 MB
    unsigned short* vTb   = (unsigned short*)(ws + 128 * MB);       // 32 MB
    unsigned short* attnb = (unsigned short*)(ws + 160 * MB);       // 32 MB

    cvt_f32_bf16<<<16384, 256, 0, stream>>>(x, xb, 4194304);
    tcvt<<<dim3(192, 64), 256, 0, stream>>>(wqkv, wqkvT, 2048, 6144);
    tcvt<<<dim3(64, 64), 256, 0, stream>>>(wo, woT, 2048, 2048);
    gemmw<1><<<dim3(24, 32), 1024, 0, stream>>>(xb, wqkvT, 8192, 6144, 2048,
                                                nullptr, qb, kb, vTb, ropeC, ropeS, 8, 12);
    attn_fwd<<<dim3(64, 8), 256, 0, stream>>>(qb, kb, vTb, attnb);
    gemmw<0><<<dim3(8, 32), 1024, 0, stream>>>(attnb, woT, 8192, 2048, 2048,
                                               out, nullptr, nullptr, nullptr, nullptr, nullptr, 4, 8);
}